// Round 4
// baseline (596.459 us; speedup 1.0000x reference)
//
#include <hip/hip_runtime.h>
#include <math.h>

#define B_ 2
#define N_ 1024
#define H_ 8
#define TOTV 5104   // compact bank vectors per (b,h)

typedef __attribute__((ext_vector_type(8))) short bf16x8;
typedef __attribute__((ext_vector_type(4))) float f32x4;

__device__ __constant__ int VBASE[11] = {0,1024,2048,3072,4096,4608,4864,4992,5056,5088,5104};

constexpr int vbase_of(int d) {
  int v = 0;
  for (int i = 0; i < d; ++i) v += (1024 >> i) * ((i >= 3) ? 8 : (1 << i));
  return v;
}

// ---------------- helpers ----------------
__device__ __forceinline__ float wsum(float v) {
  v += __shfl_xor(v, 1);  v += __shfl_xor(v, 2);  v += __shfl_xor(v, 4);
  v += __shfl_xor(v, 8);  v += __shfl_xor(v, 16); v += __shfl_xor(v, 32);
  return v;
}
__device__ __forceinline__ float sigmoidf_(float x) { return 1.f / (1.f + __expf(-x)); }
__device__ __forceinline__ unsigned short f2b(float f) {
  unsigned u = __float_as_uint(f);
  return (unsigned short)((u + 0x7FFFu + ((u >> 16) & 1u)) >> 16);
}
__device__ __forceinline__ float b2f(unsigned short h) {
  return __uint_as_float(((unsigned)h) << 16);
}
__device__ __forceinline__ float dot4(float4 a, float4 b) {
  return a.x*b.x + a.y*b.y + a.z*b.z + a.w*b.w;
}

// ---------------- fused prep: splitA(x) | splitB5(w) | splitB(oW) | build_w2b ----------------
__global__ void prep_kernel(const float* __restrict__ x,
                            const float* __restrict__ w0, const float* __restrict__ w1,
                            const float* __restrict__ w2, const float* __restrict__ w3,
                            const float* __restrict__ w4, const float* __restrict__ oW,
                            const float* __restrict__ ddqW, const float* __restrict__ ddqT,
                            unsigned short* __restrict__ A2x, unsigned short* __restrict__ B2w,
                            unsigned short* __restrict__ B2o, unsigned short* __restrict__ B2q)
{
  const int bx = blockIdx.x;
  const int tid = threadIdx.x;
  if (bx < 1024) {
    // split x: A-side PAT0 [hi|lo|hi], K=512
    int i = (bx * 256 + tid) * 4;
    int m = i >> 9, k = i & 511;
    float4 f = *(const float4*)(x + i);
    float fv[4] = {f.x, f.y, f.z, f.w};
    unsigned short h[4], l[4];
#pragma unroll
    for (int j = 0; j < 4; ++j) { h[j] = f2b(fv[j]); l[j] = f2b(fv[j] - b2f(h[j])); }
    size_t base = (size_t)m * 1536;
    ushort4 hv = {h[0], h[1], h[2], h[3]};
    ushort4 lv = {l[0], l[1], l[2], l[3]};
    *(ushort4*)(A2x + base + k) = hv;
    *(ushort4*)(A2x + base + 512 + k) = lv;
    *(ushort4*)(A2x + base + 1024 + k) = hv;
  } else if (bx < 2304) {
    // split 5 proj weights: B-side PAT1 [hi|hi|lo]
    int i = ((bx - 1024) * 256 + tid) * 4;
    int nrow = i >> 9, k = i & 511;
    int sel = nrow >> 9;
    const float* w = sel == 0 ? w0 : sel == 1 ? w1 : sel == 2 ? w2 : sel == 3 ? w3 : w4;
    float4 f = *(const float4*)(w + (size_t)(nrow & 511) * 512 + k);
    float fv[4] = {f.x, f.y, f.z, f.w};
    unsigned short h[4], l[4];
#pragma unroll
    for (int j = 0; j < 4; ++j) { h[j] = f2b(fv[j]); l[j] = f2b(fv[j] - b2f(h[j])); }
    size_t base = (size_t)nrow * 1536;
    ushort4 hv = {h[0], h[1], h[2], h[3]};
    ushort4 lv = {l[0], l[1], l[2], l[3]};
    *(ushort4*)(B2w + base + k) = hv;
    *(ushort4*)(B2w + base + 512 + k) = hv;
    *(ushort4*)(B2w + base + 1024 + k) = lv;
  } else if (bx < 2560) {
    // split oW: B-side PAT1
    int i = ((bx - 2304) * 256 + tid) * 4;
    int m = i >> 9, k = i & 511;
    float4 f = *(const float4*)(oW + i);
    float fv[4] = {f.x, f.y, f.z, f.w};
    unsigned short h[4], l[4];
#pragma unroll
    for (int j = 0; j < 4; ++j) { h[j] = f2b(fv[j]); l[j] = f2b(fv[j] - b2f(h[j])); }
    size_t base = (size_t)m * 1536;
    ushort4 hv = {h[0], h[1], h[2], h[3]};
    ushort4 lv = {l[0], l[1], l[2], l[3]};
    *(ushort4*)(B2o + base + k) = hv;
    *(ushort4*)(B2o + base + 512 + k) = hv;
    *(ushort4*)(B2o + base + 1024 + k) = lv;
  } else {
    // W2 = (ddqW[p]+I)*sc_d[p] -> B-side PAT1, K=64
    int i = (bx - 2560) * 256 + tid;
    int row = i >> 6, e = i & 63;
    int p = row >> 6, o = row & 63;
    float t = ddqT[p];
    float sp = log1pf(__expf(t));
    float scd = 1.f / ((sp + 1e-6f) * 8.0f);
    float w = (ddqW[(size_t)(p * 64 + o) * 64 + e] + (o == e ? 1.f : 0.f)) * scd;
    unsigned short h = f2b(w);
    unsigned short l = f2b(w - b2f(h));
    size_t base = (size_t)row * 192;
    B2q[base + e] = h; B2q[base + 64 + e] = h; B2q[base + 128 + e] = l;
  }
}

// ---------------- MFMA GEMM ----------------
template<int MODE>
__global__ __launch_bounds__(256)
void gemm_mfma(const unsigned short* __restrict__ A2, const unsigned short* __restrict__ B2,
               int K3,
               const float* __restrict__ bq, const float* __restrict__ bv,
               const float* __restrict__ bkl, const float* __restrict__ bvl,
               const float* __restrict__ bgt,
               float* __restrict__ qbuf, float* __restrict__ bank,
               float* __restrict__ klbuf, float* __restrict__ vlbuf,
               float* __restrict__ gatebuf, float* __restrict__ Qs,
               float* __restrict__ oout, const float* __restrict__ ob,
               unsigned short* __restrict__ A2q)
{
  __shared__ __align__(16) unsigned short Asb[128 * 40];
  __shared__ __align__(16) unsigned short Bsb[128 * 40];
  const int tid = threadIdx.x;
  const int wave = tid >> 6, lane = tid & 63;
  const int wr = wave >> 1, wc = wave & 1;
  const int row0 = blockIdx.y * 128, col0 = blockIdx.x * 128;

  f32x4 acc[4][4];
#pragma unroll
  for (int i = 0; i < 4; ++i)
#pragma unroll
    for (int j = 0; j < 4; ++j) acc[i][j] = (f32x4){0.f, 0.f, 0.f, 0.f};

  const int srow = tid >> 1;
  const int shalf = tid & 1;
  const unsigned short* agp = A2 + (size_t)(row0 + srow) * K3 + shalf * 16;
  const unsigned short* bgp = B2 + (size_t)(col0 + srow) * K3 + shalf * 16;
  const int lrow = lane & 15, kslot = lane >> 4;

  for (int kt = 0; kt < K3; kt += 32) {
    int4 a0 = *(const int4*)(agp + kt);
    int4 a1 = *(const int4*)(agp + kt + 8);
    int4 b0 = *(const int4*)(bgp + kt);
    int4 b1 = *(const int4*)(bgp + kt + 8);
    __syncthreads();
    *(int4*)(Asb + srow * 40 + shalf * 16) = a0;
    *(int4*)(Asb + srow * 40 + shalf * 16 + 8) = a1;
    *(int4*)(Bsb + srow * 40 + shalf * 16) = b0;
    *(int4*)(Bsb + srow * 40 + shalf * 16 + 8) = b1;
    __syncthreads();
    bf16x8 af[4], bf[4];
#pragma unroll
    for (int m = 0; m < 4; ++m)
      af[m] = *(const bf16x8*)(Asb + (wr * 64 + m * 16 + lrow) * 40 + kslot * 8);
#pragma unroll
    for (int n = 0; n < 4; ++n)
      bf[n] = *(const bf16x8*)(Bsb + (wc * 64 + n * 16 + lrow) * 40 + kslot * 8);
#pragma unroll
    for (int m = 0; m < 4; ++m)
#pragma unroll
      for (int n = 0; n < 4; ++n)
        acc[m][n] = __builtin_amdgcn_mfma_f32_16x16x32_bf16(af[m], bf[n], acc[m][n], 0, 0, 0);
  }

#pragma unroll
  for (int m = 0; m < 4; ++m)
#pragma unroll
    for (int n = 0; n < 4; ++n)
#pragma unroll
      for (int r = 0; r < 4; ++r) {
        const int row = row0 + wr * 64 + m * 16 + (lane >> 4) * 4 + r;
        const int col = col0 + wc * 64 + n * 16 + (lane & 15);
        float v = acc[m][n][r];
        if (MODE == 0) {
          const int sel = col >> 9;
          const int c = col & 511;
          const int bb = row >> 10, nn = row & 1023;
          if (sel == 0) {
            float vv = v + bq[c];
            qbuf[(size_t)row * 512 + c] = vv;
            unsigned short hi = f2b(vv), lo = f2b(vv - b2f(hi));
            size_t mq = (size_t)row * 8 + (c >> 6);
            int kq = c & 63;
            A2q[mq * 192 + kq] = hi;
            A2q[mq * 192 + 64 + kq] = lo;
            A2q[mq * 192 + 128 + kq] = hi;
          } else if (sel == 1) {
            bank[((size_t)(bb * 8 + (c >> 6)) * TOTV + nn) * 64 + (c & 63)] = v + bv[c];
          } else if (sel == 2) {
            klbuf[(size_t)row * 512 + c] = v + bkl[c];
          } else if (sel == 3) {
            vlbuf[(size_t)row * 512 + c] = v + bvl[c];
          } else {
            gatebuf[(size_t)row * 512 + c] = sigmoidf_(v + bgt[c]);
          }
        } else if (MODE == 1) {
          Qs[((size_t)(col >> 6) * 16384 + row) * 64 + (col & 63)] = v;
        } else {
          oout[(size_t)row * 512 + col] = v + ob[col];
        }
      }
}

// ---------------- tree level update v3 ----------------
template<int D, int NPB, bool STW>
__global__ __launch_bounds__(512)
void level3(const float* __restrict__ glW, const float* __restrict__ glb,
            const float* __restrict__ grW, const float* __restrict__ grb,
            const float* __restrict__ pq, const float* __restrict__ lnG,
            const float* __restrict__ lnB, const float* __restrict__ skA,
            const float* __restrict__ skW, const float* __restrict__ coup,
            const float* __restrict__ wfreq, const float* __restrict__ wdamp,
            const float* __restrict__ wphase, float* __restrict__ bank)
{
  constexpr int KPREV = ((D - 1) >= 3) ? 8 : (1 << (D - 1));
  constexpr int SLOTS = 2 * KPREV;
  constexpr int KP = (D >= 3) ? 8 : (1 << D);
  constexpr bool TP = (D >= 3);          // transposed pooling
  constexpr int VB_PREV = vbase_of(D - 1);
  constexpr int VB_CUR  = vbase_of(D);

  __shared__ __align__(16) float wl [STW ? 32 * 256 : 1];
  __shared__ __align__(16) float wrr[STW ? 32 * 256 : 1];
  __shared__ __align__(16) float wsk[STW ? 16 * 256 : 1];
  __shared__ __align__(16) float gin[8][128];
  __shared__ float parlds[8][KP][64];
  __shared__ __align__(16) float slds[TP ? 8 * SLOTS * 68 : 1];
  __shared__ float wlds[TP ? 8 * KP * 17 : 1];
  __shared__ __align__(16) float pqlds[TP ? KP * 68 : 1];

  const int tid = threadIdx.x;
  const int h = tid >> 6, lane = tid & 63;

  if constexpr (STW) {
    for (int i = tid; i < 64 * 128; i += 512) {
      int o = i >> 7, e = i & 127;
      wl [(e >> 2) * 256 + o * 4 + (e & 3)] = glW[(size_t)D * 8192 + i];
      wrr[(e >> 2) * 256 + o * 4 + (e & 3)] = grW[(size_t)D * 8192 + i];
    }
    for (int i = tid; i < 64 * 64; i += 512) {
      int o = i >> 6, e = i & 63;
      wsk[(e >> 2) * 256 + o * 4 + (e & 3)] = skW[(size_t)D * 4096 + i];
    }
  }
  if constexpr (TP) {
    for (int i = tid; i < KP * 64; i += 512)
      pqlds[(i >> 6) * 68 + (i & 63)] = pq[(size_t)D * 512 + i];
  }
  __syncthreads();

  const float alpha = log1pf(__expf(wdamp[h]));
  const float dec = __expf(-alpha);
  const float ang = wfreq[h] + wphase[h] + (float)D * 0.78539816339744831f;
  const float pr  = dec * cosf(ang);
  const float pim = dec * sinf(ang);
  const float glbv = glb[D * 64 + lane], grbv = grb[D * 64 + lane];
  const float lnGv = lnG[D * 64 + lane], lnBv = lnB[D * 64 + lane];
  const float sig_sk = sigmoidf_(skA[D]);
  float cw[8];
  float cmx = -1e30f;
#pragma unroll
  for (int j = 0; j < 8; ++j) { cw[j] = coup[(size_t)(D * 8 + h) * 8 + j]; cmx = fmaxf(cmx, cw[j]); }
  float cs = 0.f;
#pragma unroll
  for (int j = 0; j < 8; ++j) { cw[j] = __expf(cw[j] - cmx); cs += cw[j]; }
  const float cinv = 1.f / cs;

  const size_t bh = (size_t)blockIdx.y * 8 + h;
  const float* prevb = bank + (bh * TOTV + VB_PREV) * 64;
  float* curb = bank + (bh * TOTV + VB_CUR) * 64;

  for (int nn = 0; nn < NPB; ++nn) {
    const int node = blockIdx.x * NPB + nn;
    float par[KP];
    {
      float fL[KPREV], rot[KPREV];
      float lm = 0.f, rm = 0.f;
#pragma unroll
      for (int k = 0; k < KPREV; ++k) {
        fL[k] = prevb[(size_t)((2 * node) * KPREV + k) * 64 + lane];
        float fr = prevb[(size_t)((2 * node + 1) * KPREV + k) * 64 + lane];
        float partner = __shfl_xor(fr, 32);
        rot[k] = (lane < 32) ? (pr * fr - pim * partner) : (pim * partner + pr * fr);
        lm += fL[k]; rm += rot[k];
      }
      lm *= (1.f / KPREV); rm *= (1.f / KPREV);
      gin[h][lane] = lm;
      gin[h][64 + lane] = rm;     // wave-local

      float gl = glbv, gr = grbv, sk = 0.f;
      if constexpr (STW) {
#pragma unroll
        for (int eg = 0; eg < 32; ++eg) {
          float4 g4 = *(const float4*)&gin[h][eg * 4];
          gl += dot4(g4, *(const float4*)&wl [eg * 256 + lane * 4]);
          gr += dot4(g4, *(const float4*)&wrr[eg * 256 + lane * 4]);
          if (eg < 16) sk += dot4(g4, *(const float4*)&wsk[eg * 256 + lane * 4]);
        }
      } else {
        const float* wg = glW + (size_t)D * 8192 + lane * 128;
        const float* wr2 = grW + (size_t)D * 8192 + lane * 128;
        const float* ws2 = skW + (size_t)D * 4096 + lane * 64;
#pragma unroll
        for (int eg = 0; eg < 32; ++eg) {
          float4 g4 = *(const float4*)&gin[h][eg * 4];
          gl += dot4(g4, *(const float4*)&wg[eg * 4]);
          gr += dot4(g4, *(const float4*)&wr2[eg * 4]);
          if (eg < 16) sk += dot4(g4, *(const float4*)&ws2[eg * 4]);
        }
      }
      gl = sigmoidf_(gl); gr = sigmoidf_(gr);

      float slot[SLOTS];
#pragma unroll
      for (int k = 0; k < KPREV; ++k) { slot[k] = fL[k] * gl; slot[KPREV + k] = rot[k] * gr; }

      if constexpr (!TP) {
        float pqv[KP];
#pragma unroll
        for (int qi = 0; qi < KP; ++qi) pqv[qi] = pq[(size_t)(D * 8 + qi) * 64 + lane];
#pragma unroll
        for (int qi = 0; qi < KP; ++qi) {
          float lg[SLOTS];
          float mx = -1e30f;
#pragma unroll
          for (int kk = 0; kk < SLOTS; ++kk) {
            lg[kk] = wsum(pqv[qi] * slot[kk]) * 0.125f;
            mx = fmaxf(mx, lg[kk]);
          }
          float den = 0.f, pv = 0.f;
#pragma unroll
          for (int kk = 0; kk < SLOTS; ++kk) {
            float w = __expf(lg[kk] - mx);
            den += w; pv += w * slot[kk];
          }
          par[qi] = pv / den;
        }
      } else {
        // transposed pooling: lane handles (qi,kk) pairs
        float* sl = &slds[h * SLOTS * 68];
#pragma unroll
        for (int kk = 0; kk < SLOTS; ++kk) sl[kk * 68 + lane] = slot[kk];
        constexpr int PAIRS = KP * SLOTS;   // 64 (D=3) or 128 (D>=4)
        const int kk0 = lane & (SLOTS - 1);
        const int qg  = lane / SLOTS;       // lane group
        float s0 = 0.f, s1 = 0.f;
        {
          const float4* sv = (const float4*)&sl[kk0 * 68];
          const float4* q0 = (const float4*)&pqlds[qg * 68];
#pragma unroll
          for (int e = 0; e < 16; ++e) s0 += dot4(q0[e], sv[e]);
          if constexpr (PAIRS == 128) {
            const float4* q1 = (const float4*)&pqlds[(qg + 4) * 68];
#pragma unroll
            for (int e = 0; e < 16; ++e) s1 += dot4(q1[e], sv[e]);
          }
        }
        s0 *= 0.125f; s1 *= 0.125f;
        float m0 = s0, m1 = s1;
#pragma unroll
        for (int o = 1; o < SLOTS; o <<= 1) {
          m0 = fmaxf(m0, __shfl_xor(m0, o));
          if constexpr (PAIRS == 128) m1 = fmaxf(m1, __shfl_xor(m1, o));
        }
        float e0 = __expf(s0 - m0), e1 = (PAIRS == 128) ? __expf(s1 - m1) : 0.f;
        float d0 = e0, d1 = e1;
#pragma unroll
        for (int o = 1; o < SLOTS; o <<= 1) {
          d0 += __shfl_xor(d0, o);
          if constexpr (PAIRS == 128) d1 += __shfl_xor(d1, o);
        }
        float* wld = &wlds[h * KP * 17];
        wld[qg * 17 + kk0] = e0 / d0;
        if constexpr (PAIRS == 128) wld[(qg + 4) * 17 + kk0] = e1 / d1;
#pragma unroll
        for (int qi = 0; qi < KP; ++qi) {
          float acc2 = 0.f;
#pragma unroll
          for (int kk = 0; kk < SLOTS; ++kk) acc2 += wld[qi * 17 + kk] * slot[kk];
          par[qi] = acc2;
        }
      }

      // LN + skip
#pragma unroll
      for (int qi = 0; qi < KP; ++qi) {
        float mu = wsum(par[qi]) * (1.f / 64.f);
        float dv = par[qi] - mu;
        float var = wsum(dv * dv) * (1.f / 64.f);
        float nv = dv * rsqrtf(var + 1e-5f);
        par[qi] = nv * lnGv + lnBv + sig_sk * sk;
        parlds[h][qi][lane] = par[qi];
      }
    }
    __syncthreads();
#pragma unroll
    for (int qi = 0; qi < KP; ++qi) {
      float o = 0.f;
#pragma unroll
      for (int j = 0; j < 8; ++j) o += cw[j] * parlds[j][qi][lane];
      curb[(size_t)(node * KP + qi) * 64 + lane] = o * cinv;
    }
    __syncthreads();
  }
}

// ---------------- combine v2: lane-parallel local attn + tree attn + fused split epilogue ----
__global__ __launch_bounds__(512)
void combine2(const float* __restrict__ qbuf, const float* __restrict__ klbuf,
              const float* __restrict__ vlbuf, const float* __restrict__ gatebuf,
              const float* __restrict__ bank, const float* __restrict__ Qs,
              unsigned short* __restrict__ A2o)
{
  const int n = blockIdx.x;
  const int b = blockIdx.y;
  const int h = threadIdx.x >> 6;
  const int lane = threadIdx.x & 63;
  __shared__ int pair_ro[64];
  __shared__ int pair_sl[64];
  __shared__ int sdepth[16];
  __shared__ int PS[2];
  __shared__ __align__(16) float Qlds[8][10][68];
  __shared__ __align__(16) float qlds[8][64];

  if (threadIdx.x == 0) {
    int l = 2048, r = 2048 + n;
    int cnt = 0, sc = 0;
    while (l < r) {
      if (l & 1) {
        int m = l++;
        int j = 31 - __clz(m);
        int d = 11 - j;
        int local = m - (1 << j);
        int kv = (d >= 3) ? 8 : (1 << d);
        sdepth[sc] = d;
        int vb = VBASE[d] + local * kv;
        for (int k = 0; k < kv; ++k) { pair_ro[cnt] = (vb + k) * 64; pair_sl[cnt] = sc; ++cnt; }
        ++sc;
      }
      if (r & 1) {
        int m = --r;
        int j = 31 - __clz(m);
        int d = 11 - j;
        int local = m - (1 << j);
        int kv = (d >= 3) ? 8 : (1 << d);
        sdepth[sc] = d;
        int vb = VBASE[d] + local * kv;
        for (int k = 0; k < kv; ++k) { pair_ro[cnt] = (vb + k) * 64; pair_sl[cnt] = sc; ++cnt; }
        ++sc;
      }
      l >>= 1; r >>= 1;
    }
    PS[0] = cnt; PS[1] = sc;
  }
  const size_t vbase = ((size_t)(b * N_ + n) * H_ + h) * 64;
  qlds[h][lane] = qbuf[vbase + lane];   // wave-local
  __syncthreads();
  const int P = PS[0], S = PS[1];

  for (int s = 0; s < S; ++s)
    Qlds[h][s][lane] = Qs[((size_t)sdepth[s] * 16384 + (size_t)(b * N_ + n) * H_ + h) * 64 + lane];
  // Qlds[h]/qlds[h] only read by wave h -> no barrier needed

  // ---- local sliding-window attention, lane-parallel scores ----
  const int w = lane & 31, half = lane >> 5;
  const int wmax = (n + 1 < 32) ? (n + 1) : 32;
  float sc = 0.f;
  if (w < wmax) {
    const float4* k4 = (const float4*)(klbuf + vbase - (size_t)w * 512 + half * 32);
    const float4* q4 = (const float4*)&qlds[h][half * 32];
#pragma unroll
    for (int e = 0; e < 8; ++e) sc += dot4(q4[e], k4[e]);
  }
  sc += __shfl_xor(sc, 32);
  sc *= 0.125f;
  float sm = (w < wmax) ? sc : -1e30f;
  float mx = sm;
#pragma unroll
  for (int o = 1; o < 32; o <<= 1) mx = fmaxf(mx, __shfl_xor(mx, o));
  float le = (w < wmax) ? __expf(sm - mx) : 0.f;
  float den = le;
#pragma unroll
  for (int o = 1; o < 32; o <<= 1) den += __shfl_xor(den, o);
  float lp = le / den;
  float local = 0.f;
  for (int ww = 0; ww < wmax; ++ww) {
    float pw = __shfl(lp, ww);
    local += pw * vlbuf[vbase - (size_t)ww * 512 + lane];
  }

  // ---- tree attention ----
  const size_t bhbase = (size_t)(b * H_ + h) * TOTV * 64;
  float tree = 0.f;
  if (P > 0) {
    float logit = -1e30f;
    if (lane < P) {
      const float4* b4 = (const float4*)(bank + bhbase + pair_ro[lane]);
      const float4* q4 = (const float4*)&Qlds[h][pair_sl[lane]][0];
      float a = 0.f;
#pragma unroll
      for (int i = 0; i < 16; ++i) a += dot4(q4[i], b4[i]);
      logit = a;
    }
    float tm = logit;
#pragma unroll
    for (int o = 1; o < 64; o <<= 1) tm = fmaxf(tm, __shfl_xor(tm, o));
    float te = (lane < P) ? __expf(logit - tm) : 0.f;
    float tden = te;
#pragma unroll
    for (int o = 1; o < 64; o <<= 1) tden += __shfl_xor(tden, o);
    float tw = te / tden;
    for (int l2 = 0; l2 < P; ++l2) {
      float wl_ = __shfl(tw, l2);
      tree += wl_ * bank[bhbase + pair_ro[l2] + lane];
    }
  }

  // ---- gate + fused split-bf16 epilogue (A-side PAT0 [hi|lo|hi], K=512) ----
  float g = gatebuf[vbase + lane];
  float v = local + g * tree;
  unsigned short hi = f2b(v), lo = f2b(v - b2f(hi));
  const size_t m = (size_t)(b * N_ + n);
  const int k = h * 64 + lane;
  A2o[m * 1536 + k] = hi;
  A2o[m * 1536 + 512 + k] = lo;
  A2o[m * 1536 + 1024 + k] = hi;
}

// ---------------- launcher ----------------
extern "C" void kernel_launch(void* const* d_in, const int* in_sizes, int n_in,
                              void* d_out, int out_size, void* d_ws, size_t ws_size,
                              hipStream_t stream)
{
  (void)in_sizes; (void)n_in; (void)out_size; (void)ws_size;
  const float* x     = (const float*)d_in[0];
  const float* qW    = (const float*)d_in[1];
  const float* qb    = (const float*)d_in[2];
  const float* vW    = (const float*)d_in[3];
  const float* vb    = (const float*)d_in[4];
  const float* oW    = (const float*)d_in[5];
  const float* ob    = (const float*)d_in[6];
  const float* klW   = (const float*)d_in[7];
  const float* klb   = (const float*)d_in[8];
  const float* vlW   = (const float*)d_in[9];
  const float* vlb   = (const float*)d_in[10];
  const float* gW    = (const float*)d_in[11];
  const float* gb    = (const float*)d_in[12];
  const float* ddqW  = (const float*)d_in[13];
  const float* ddqT  = (const float*)d_in[14];
  const float* wfreq = (const float*)d_in[15];
  const float* wdamp = (const float*)d_in[16];
  const float* wphase= (const float*)d_in[17];
  const float* glW   = (const float*)d_in[18];
  const float* glb   = (const float*)d_in[19];
  const float* grW   = (const float*)d_in[20];
  const float* grb   = (const float*)d_in[21];
  const float* pq    = (const float*)d_in[22];
  const float* lnG   = (const float*)d_in[23];
  const float* lnB   = (const float*)d_in[24];
  const float* skA   = (const float*)d_in[25];
  const float* skW   = (const float*)d_in[26];
  const float* coup  = (const float*)d_in[27];

  float* ws = (float*)d_ws;
  float* qbuf    = ws; ws += (size_t)2048 * 512;
  float* klbuf   = ws; ws += (size_t)2048 * 512;
  float* vlbuf   = ws; ws += (size_t)2048 * 512;
  float* gatebuf = ws; ws += (size_t)2048 * 512;
  float* bank    = ws; ws += (size_t)16 * TOTV * 64;
  float* Qs      = ws; ws += (size_t)10 * 16384 * 64;
  unsigned short* A2x = (unsigned short*)ws; ws += (size_t)2048 * 1536 / 2;
  unsigned short* B2w = (unsigned short*)ws; ws += (size_t)2560 * 1536 / 2;
  unsigned short* A2q = (unsigned short*)ws; ws += (size_t)16384 * 192 / 2;
  unsigned short* B2q = (unsigned short*)ws; ws += (size_t)640 * 192 / 2;
  unsigned short* A2o = (unsigned short*)ws; ws += (size_t)2048 * 1536 / 2;
  unsigned short* B2o = (unsigned short*)ws; ws += (size_t)512 * 1536 / 2;

  prep_kernel<<<2720, 256, 0, stream>>>(x, qW, vW, klW, vlW, gW, oW, ddqW, ddqT,
                                        A2x, B2w, B2o, B2q);

  gemm_mfma<0><<<dim3(20, 16), 256, 0, stream>>>(A2x, B2w, 1536,
      qb, vb, klb, vlb, gb, qbuf, bank, klbuf, vlbuf, gatebuf,
      nullptr, nullptr, nullptr, A2q);

  gemm_mfma<1><<<dim3(5, 128), 256, 0, stream>>>(A2q, B2q, 192,
      nullptr, nullptr, nullptr, nullptr, nullptr,
      nullptr, nullptr, nullptr, nullptr, nullptr, Qs, nullptr, nullptr, nullptr);

#define LVL(DD, NPB, STW) level3<DD, NPB, STW><<<dim3((1024 >> DD) / NPB, 2), 512, 0, stream>>>( \
      glW, glb, grW, grb, pq, lnG, lnB, skA, skW, coup, wfreq, wdamp, wphase, bank)
  LVL(1, 8, true); LVL(2, 4, true); LVL(3, 2, true);
  LVL(4, 1, false); LVL(5, 1, false); LVL(6, 1, false);
  LVL(7, 1, false); LVL(8, 1, false); LVL(9, 1, false);
#undef LVL

  combine2<<<dim3(1024, 2), 512, 0, stream>>>(qbuf, klbuf, vlbuf, gatebuf, bank, Qs, A2o);

  gemm_mfma<2><<<dim3(4, 16), 256, 0, stream>>>(A2o, B2o, 1536,
      nullptr, nullptr, nullptr, nullptr, nullptr,
      nullptr, nullptr, nullptr, nullptr, nullptr, nullptr,
      (float*)d_out, ob, nullptr);
}

// Round 5
// 594.874 us; speedup vs baseline: 1.0027x; 1.0027x over previous
//
#include <hip/hip_runtime.h>
#include <math.h>

#define B_ 2
#define N_ 1024
#define H_ 8
#define TOTV 5104   // compact bank vectors per (b,h)

typedef __attribute__((ext_vector_type(8))) short bf16x8;
typedef __attribute__((ext_vector_type(4))) float f32x4;

__device__ __constant__ int VBASE[11] = {0,1024,2048,3072,4096,4608,4864,4992,5056,5088,5104};

constexpr int vbase_of(int d) {
  int v = 0;
  for (int i = 0; i < d; ++i) v += (1024 >> i) * ((i >= 3) ? 8 : (1 << i));
  return v;
}

// ---------------- helpers ----------------
__device__ __forceinline__ float wsum(float v) {
  v += __shfl_xor(v, 1);  v += __shfl_xor(v, 2);  v += __shfl_xor(v, 4);
  v += __shfl_xor(v, 8);  v += __shfl_xor(v, 16); v += __shfl_xor(v, 32);
  return v;
}
__device__ __forceinline__ float sigmoidf_(float x) { return 1.f / (1.f + __expf(-x)); }
__device__ __forceinline__ unsigned short f2b(float f) {
  unsigned u = __float_as_uint(f);
  return (unsigned short)((u + 0x7FFFu + ((u >> 16) & 1u)) >> 16);
}
__device__ __forceinline__ float b2f(unsigned short h) {
  return __uint_as_float(((unsigned)h) << 16);
}
__device__ __forceinline__ float dot4(float4 a, float4 b) {
  return a.x*b.x + a.y*b.y + a.z*b.z + a.w*b.w;
}

// ---------------- fused prep: splitA(x) | splitB5(w) | splitB(oW) | build_w2b ----------------
__global__ void prep_kernel(const float* __restrict__ x,
                            const float* __restrict__ w0, const float* __restrict__ w1,
                            const float* __restrict__ w2, const float* __restrict__ w3,
                            const float* __restrict__ w4, const float* __restrict__ oW,
                            const float* __restrict__ ddqW, const float* __restrict__ ddqT,
                            unsigned short* __restrict__ A2x, unsigned short* __restrict__ B2w,
                            unsigned short* __restrict__ B2o, unsigned short* __restrict__ B2q)
{
  const int bx = blockIdx.x;
  const int tid = threadIdx.x;
  if (bx < 1024) {
    int i = (bx * 256 + tid) * 4;
    int m = i >> 9, k = i & 511;
    float4 f = *(const float4*)(x + i);
    float fv[4] = {f.x, f.y, f.z, f.w};
    unsigned short h[4], l[4];
#pragma unroll
    for (int j = 0; j < 4; ++j) { h[j] = f2b(fv[j]); l[j] = f2b(fv[j] - b2f(h[j])); }
    size_t base = (size_t)m * 1536;
    ushort4 hv = {h[0], h[1], h[2], h[3]};
    ushort4 lv = {l[0], l[1], l[2], l[3]};
    *(ushort4*)(A2x + base + k) = hv;
    *(ushort4*)(A2x + base + 512 + k) = lv;
    *(ushort4*)(A2x + base + 1024 + k) = hv;
  } else if (bx < 2304) {
    int i = ((bx - 1024) * 256 + tid) * 4;
    int nrow = i >> 9, k = i & 511;
    int sel = nrow >> 9;
    const float* w = sel == 0 ? w0 : sel == 1 ? w1 : sel == 2 ? w2 : sel == 3 ? w3 : w4;
    float4 f = *(const float4*)(w + (size_t)(nrow & 511) * 512 + k);
    float fv[4] = {f.x, f.y, f.z, f.w};
    unsigned short h[4], l[4];
#pragma unroll
    for (int j = 0; j < 4; ++j) { h[j] = f2b(fv[j]); l[j] = f2b(fv[j] - b2f(h[j])); }
    size_t base = (size_t)nrow * 1536;
    ushort4 hv = {h[0], h[1], h[2], h[3]};
    ushort4 lv = {l[0], l[1], l[2], l[3]};
    *(ushort4*)(B2w + base + k) = hv;
    *(ushort4*)(B2w + base + 512 + k) = hv;
    *(ushort4*)(B2w + base + 1024 + k) = lv;
  } else if (bx < 2560) {
    int i = ((bx - 2304) * 256 + tid) * 4;
    int m = i >> 9, k = i & 511;
    float4 f = *(const float4*)(oW + i);
    float fv[4] = {f.x, f.y, f.z, f.w};
    unsigned short h[4], l[4];
#pragma unroll
    for (int j = 0; j < 4; ++j) { h[j] = f2b(fv[j]); l[j] = f2b(fv[j] - b2f(h[j])); }
    size_t base = (size_t)m * 1536;
    ushort4 hv = {h[0], h[1], h[2], h[3]};
    ushort4 lv = {l[0], l[1], l[2], l[3]};
    *(ushort4*)(B2o + base + k) = hv;
    *(ushort4*)(B2o + base + 512 + k) = hv;
    *(ushort4*)(B2o + base + 1024 + k) = lv;
  } else {
    int i = (bx - 2560) * 256 + tid;
    int row = i >> 6, e = i & 63;
    int p = row >> 6, o = row & 63;
    float t = ddqT[p];
    float sp = log1pf(__expf(t));
    float scd = 1.f / ((sp + 1e-6f) * 8.0f);
    float w = (ddqW[(size_t)(p * 64 + o) * 64 + e] + (o == e ? 1.f : 0.f)) * scd;
    unsigned short h = f2b(w);
    unsigned short l = f2b(w - b2f(h));
    size_t base = (size_t)row * 192;
    B2q[base + e] = h; B2q[base + 64 + e] = h; B2q[base + 128 + e] = l;
  }
}

// ---------------- MFMA GEMM ----------------
template<int MODE>
__global__ __launch_bounds__(256)
void gemm_mfma(const unsigned short* __restrict__ A2, const unsigned short* __restrict__ B2,
               int K3,
               const float* __restrict__ bq, const float* __restrict__ bv,
               const float* __restrict__ bkl, const float* __restrict__ bvl,
               const float* __restrict__ bgt,
               float* __restrict__ qbuf, float* __restrict__ bank,
               float* __restrict__ klbuf, float* __restrict__ vlbuf,
               float* __restrict__ gatebuf, float* __restrict__ Qs,
               float* __restrict__ oout, const float* __restrict__ ob,
               unsigned short* __restrict__ A2q)
{
  __shared__ __align__(16) unsigned short Asb[128 * 40];
  __shared__ __align__(16) unsigned short Bsb[128 * 40];
  const int tid = threadIdx.x;
  const int wave = tid >> 6, lane = tid & 63;
  const int wr = wave >> 1, wc = wave & 1;
  const int row0 = blockIdx.y * 128, col0 = blockIdx.x * 128;

  f32x4 acc[4][4];
#pragma unroll
  for (int i = 0; i < 4; ++i)
#pragma unroll
    for (int j = 0; j < 4; ++j) acc[i][j] = (f32x4){0.f, 0.f, 0.f, 0.f};

  const int srow = tid >> 1;
  const int shalf = tid & 1;
  const unsigned short* agp = A2 + (size_t)(row0 + srow) * K3 + shalf * 16;
  const unsigned short* bgp = B2 + (size_t)(col0 + srow) * K3 + shalf * 16;
  const int lrow = lane & 15, kslot = lane >> 4;

  for (int kt = 0; kt < K3; kt += 32) {
    int4 a0 = *(const int4*)(agp + kt);
    int4 a1 = *(const int4*)(agp + kt + 8);
    int4 b0 = *(const int4*)(bgp + kt);
    int4 b1 = *(const int4*)(bgp + kt + 8);
    __syncthreads();
    *(int4*)(Asb + srow * 40 + shalf * 16) = a0;
    *(int4*)(Asb + srow * 40 + shalf * 16 + 8) = a1;
    *(int4*)(Bsb + srow * 40 + shalf * 16) = b0;
    *(int4*)(Bsb + srow * 40 + shalf * 16 + 8) = b1;
    __syncthreads();
    bf16x8 af[4], bf[4];
#pragma unroll
    for (int m = 0; m < 4; ++m)
      af[m] = *(const bf16x8*)(Asb + (wr * 64 + m * 16 + lrow) * 40 + kslot * 8);
#pragma unroll
    for (int n = 0; n < 4; ++n)
      bf[n] = *(const bf16x8*)(Bsb + (wc * 64 + n * 16 + lrow) * 40 + kslot * 8);
#pragma unroll
    for (int m = 0; m < 4; ++m)
#pragma unroll
      for (int n = 0; n < 4; ++n)
        acc[m][n] = __builtin_amdgcn_mfma_f32_16x16x32_bf16(af[m], bf[n], acc[m][n], 0, 0, 0);
  }

#pragma unroll
  for (int m = 0; m < 4; ++m)
#pragma unroll
    for (int n = 0; n < 4; ++n)
#pragma unroll
      for (int r = 0; r < 4; ++r) {
        const int row = row0 + wr * 64 + m * 16 + (lane >> 4) * 4 + r;
        const int col = col0 + wc * 64 + n * 16 + (lane & 15);
        float v = acc[m][n][r];
        if (MODE == 0) {
          const int sel = col >> 9;
          const int c = col & 511;
          const int bb = row >> 10, nn = row & 1023;
          if (sel == 0) {
            float vv = v + bq[c];
            qbuf[(size_t)row * 512 + c] = vv;
            unsigned short hi = f2b(vv), lo = f2b(vv - b2f(hi));
            size_t mq = (size_t)row * 8 + (c >> 6);
            int kq = c & 63;
            A2q[mq * 192 + kq] = hi;
            A2q[mq * 192 + 64 + kq] = lo;
            A2q[mq * 192 + 128 + kq] = hi;
          } else if (sel == 1) {
            bank[((size_t)(bb * 8 + (c >> 6)) * TOTV + nn) * 64 + (c & 63)] = v + bv[c];
          } else if (sel == 2) {
            klbuf[(size_t)row * 512 + c] = v + bkl[c];
          } else if (sel == 3) {
            vlbuf[(size_t)row * 512 + c] = v + bvl[c];
          } else {
            gatebuf[(size_t)row * 512 + c] = sigmoidf_(v + bgt[c]);
          }
        } else if (MODE == 1) {
          Qs[((size_t)(col >> 6) * 16384 + row) * 64 + (col & 63)] = v;
        } else {
          oout[(size_t)row * 512 + col] = v + ob[col];
        }
      }
}

// ---------------- tree level update v4: slim LDS, no weight staging, no conflicts ----------------
template<int D>
__global__ __launch_bounds__(512)
void level4(const float* __restrict__ glW, const float* __restrict__ glb,
            const float* __restrict__ grW, const float* __restrict__ grb,
            const float* __restrict__ pq, const float* __restrict__ lnG,
            const float* __restrict__ lnB, const float* __restrict__ skA,
            const float* __restrict__ skW, const float* __restrict__ coup,
            const float* __restrict__ wfreq, const float* __restrict__ wdamp,
            const float* __restrict__ wphase, float* __restrict__ bank)
{
  constexpr int KPREV = ((D - 1) >= 3) ? 8 : (1 << (D - 1));
  constexpr int SLOTS = 2 * KPREV;
  constexpr int KP = (D >= 3) ? 8 : (1 << D);
  constexpr bool TP = (D >= 3);
  constexpr int VB_PREV = vbase_of(D - 1);
  constexpr int VB_CUR  = vbase_of(D);

  __shared__ __align__(16) float gin[8][128];
  __shared__ float parlds[8][KP][64];
  __shared__ __align__(16) float slds[TP ? 8 * SLOTS * 68 : 1];
  __shared__ float wlds[TP ? 8 * KP * 17 : 1];
  __shared__ __align__(16) float pqlds[TP ? KP * 68 : 1];

  const int tid = threadIdx.x;
  const int h = tid >> 6, lane = tid & 63;
  const int node = blockIdx.x;
  const int b = blockIdx.y;

  if constexpr (TP) {
    for (int i = tid; i < KP * 64; i += 512)
      pqlds[(i >> 6) * 68 + (i & 63)] = pq[(size_t)D * 512 + i];
    __syncthreads();
  }

  const float alpha = log1pf(__expf(wdamp[h]));
  const float dec = __expf(-alpha);
  const float ang = wfreq[h] + wphase[h] + (float)D * 0.78539816339744831f;
  const float pr  = dec * cosf(ang);
  const float pim = dec * sinf(ang);
  const float glbv = glb[D * 64 + lane], grbv = grb[D * 64 + lane];
  const float lnGv = lnG[D * 64 + lane], lnBv = lnB[D * 64 + lane];
  const float sig_sk = sigmoidf_(skA[D]);
  float cw[8];
  float cmx = -1e30f;
#pragma unroll
  for (int j = 0; j < 8; ++j) { cw[j] = coup[(size_t)(D * 8 + h) * 8 + j]; cmx = fmaxf(cmx, cw[j]); }
  float cs = 0.f;
#pragma unroll
  for (int j = 0; j < 8; ++j) { cw[j] = __expf(cw[j] - cmx); cs += cw[j]; }
  const float cinv = 1.f / cs;

  const size_t bh = (size_t)(b * H_ + h);
  const float* prevb = bank + (bh * TOTV + VB_PREV) * 64;
  float* curb = bank + (bh * TOTV + VB_CUR) * 64;

  float par[KP];
  {
    float fL[KPREV], rot[KPREV];
    float lm = 0.f, rm = 0.f;
#pragma unroll
    for (int k = 0; k < KPREV; ++k) {
      fL[k] = prevb[(size_t)((2 * node) * KPREV + k) * 64 + lane];
      float fr = prevb[(size_t)((2 * node + 1) * KPREV + k) * 64 + lane];
      float partner = __shfl_xor(fr, 32);
      rot[k] = (lane < 32) ? (pr * fr - pim * partner) : (pim * partner + pr * fr);
      lm += fL[k]; rm += rot[k];
    }
    lm *= (1.f / KPREV); rm *= (1.f / KPREV);
    gin[h][lane] = lm;
    gin[h][64 + lane] = rm;     // wave-local write->read: safe without barrier

    // gate matvecs: lane = output row, weights from L1/L2 (row-per-lane)
    const float* wg  = glW + (size_t)D * 8192 + lane * 128;
    const float* wr2 = grW + (size_t)D * 8192 + lane * 128;
    const float* ws2 = skW + (size_t)D * 4096 + lane * 64;
    float gl = glbv, gr = grbv, sk = 0.f;
#pragma unroll 4
    for (int eg = 0; eg < 32; ++eg) {
      float4 g4 = *(const float4*)&gin[h][eg * 4];
      gl += dot4(g4, *(const float4*)&wg[eg * 4]);
      gr += dot4(g4, *(const float4*)&wr2[eg * 4]);
      if (eg < 16) sk += dot4(g4, *(const float4*)&ws2[eg * 4]);
    }
    gl = sigmoidf_(gl); gr = sigmoidf_(gr);

    float slot[SLOTS];
#pragma unroll
    for (int k = 0; k < KPREV; ++k) { slot[k] = fL[k] * gl; slot[KPREV + k] = rot[k] * gr; }

    if constexpr (!TP) {
      float pqv[KP];
#pragma unroll
      for (int qi = 0; qi < KP; ++qi) pqv[qi] = pq[(size_t)(D * 8 + qi) * 64 + lane];
#pragma unroll
      for (int qi = 0; qi < KP; ++qi) {
        float lg[SLOTS];
        float mx = -1e30f;
#pragma unroll
        for (int kk = 0; kk < SLOTS; ++kk) {
          lg[kk] = wsum(pqv[qi] * slot[kk]) * 0.125f;
          mx = fmaxf(mx, lg[kk]);
        }
        float den = 0.f, pv = 0.f;
#pragma unroll
        for (int kk = 0; kk < SLOTS; ++kk) {
          float w = __expf(lg[kk] - mx);
          den += w; pv += w * slot[kk];
        }
        par[qi] = pv / den;
      }
    } else {
      // transposed pooling: lane handles (qi,kk) pairs; stride-68 rows keep reads <=2-way
      float* sl = &slds[h * SLOTS * 68];
#pragma unroll
      for (int kk = 0; kk < SLOTS; ++kk) sl[kk * 68 + lane] = slot[kk];
      constexpr int PAIRS = KP * SLOTS;   // 64 (D=3) or 128 (D>=4)
      const int kk0 = lane & (SLOTS - 1);
      const int qg  = lane / SLOTS;
      float s0 = 0.f, s1 = 0.f;
      {
        const float4* sv = (const float4*)&sl[kk0 * 68];
        const float4* q0 = (const float4*)&pqlds[qg * 68];
#pragma unroll
        for (int e = 0; e < 16; ++e) s0 += dot4(q0[e], sv[e]);
        if constexpr (PAIRS == 128) {
          const float4* q1 = (const float4*)&pqlds[(qg + 4) * 68];
#pragma unroll
          for (int e = 0; e < 16; ++e) s1 += dot4(q1[e], sv[e]);
        }
      }
      s0 *= 0.125f; s1 *= 0.125f;
      float m0 = s0, m1 = s1;
#pragma unroll
      for (int o = 1; o < SLOTS; o <<= 1) {
        m0 = fmaxf(m0, __shfl_xor(m0, o));
        if constexpr (PAIRS == 128) m1 = fmaxf(m1, __shfl_xor(m1, o));
      }
      float e0 = __expf(s0 - m0), e1 = (PAIRS == 128) ? __expf(s1 - m1) : 0.f;
      float d0 = e0, d1 = e1;
#pragma unroll
      for (int o = 1; o < SLOTS; o <<= 1) {
        d0 += __shfl_xor(d0, o);
        if constexpr (PAIRS == 128) d1 += __shfl_xor(d1, o);
      }
      float* wld = &wlds[h * KP * 17];
      wld[qg * 17 + kk0] = e0 / d0;
      if constexpr (PAIRS == 128) wld[(qg + 4) * 17 + kk0] = e1 / d1;
#pragma unroll
      for (int qi = 0; qi < KP; ++qi) {
        float acc2 = 0.f;
#pragma unroll
        for (int kk = 0; kk < SLOTS; ++kk) acc2 += wld[qi * 17 + kk] * slot[kk];
        par[qi] = acc2;
      }
    }

    // LN + skip
#pragma unroll
    for (int qi = 0; qi < KP; ++qi) {
      float mu = wsum(par[qi]) * (1.f / 64.f);
      float dv = par[qi] - mu;
      float var = wsum(dv * dv) * (1.f / 64.f);
      float nv = dv * rsqrtf(var + 1e-5f);
      par[qi] = nv * lnGv + lnBv + sig_sk * sk;
      parlds[h][qi][lane] = par[qi];
    }
  }
  __syncthreads();
#pragma unroll
  for (int qi = 0; qi < KP; ++qi) {
    float o = 0.f;
#pragma unroll
    for (int j = 0; j < 8; ++j) o += cw[j] * parlds[j][qi][lane];
    curb[(size_t)(node * KP + qi) * 64 + lane] = o * cinv;
  }
}

// ---------------- combine v3: XCD swizzle + 4-lane score gather + unrolled PV ----------------
__global__ __launch_bounds__(512)
void combine3(const float* __restrict__ qbuf, const float* __restrict__ klbuf,
              const float* __restrict__ vlbuf, const float* __restrict__ gatebuf,
              const float* __restrict__ bank, const float* __restrict__ Qs,
              unsigned short* __restrict__ A2o)
{
  // XCD-aware swizzle: each XCD gets 256 consecutive n of one b -> cover nodes L2-local
  const int flat = blockIdx.y * 1024 + blockIdx.x;
  const int swz = (flat & 7) * 256 + (flat >> 3);
  const int n = swz & 1023;
  const int b = swz >> 10;
  const int h = threadIdx.x >> 6;
  const int lane = threadIdx.x & 63;
  __shared__ int pair_ro[64];
  __shared__ int pair_sl[64];
  __shared__ int sdepth[16];
  __shared__ int PS[2];
  __shared__ __align__(16) float Qlds[8][10][68];
  __shared__ __align__(16) float qlds[8][64];
  __shared__ float sclds[8][64];

  if (threadIdx.x == 0) {
    int l = 2048, r = 2048 + n;
    int cnt = 0, sc = 0;
    while (l < r) {
      if (l & 1) {
        int m = l++;
        int j = 31 - __clz(m);
        int d = 11 - j;
        int local = m - (1 << j);
        int kv = (d >= 3) ? 8 : (1 << d);
        sdepth[sc] = d;
        int vb = VBASE[d] + local * kv;
        for (int k = 0; k < kv; ++k) { pair_ro[cnt] = (vb + k) * 64; pair_sl[cnt] = sc; ++cnt; }
        ++sc;
      }
      if (r & 1) {
        int m = --r;
        int j = 31 - __clz(m);
        int d = 11 - j;
        int local = m - (1 << j);
        int kv = (d >= 3) ? 8 : (1 << d);
        sdepth[sc] = d;
        int vb = VBASE[d] + local * kv;
        for (int k = 0; k < kv; ++k) { pair_ro[cnt] = (vb + k) * 64; pair_sl[cnt] = sc; ++cnt; }
        ++sc;
      }
      l >>= 1; r >>= 1;
    }
    PS[0] = cnt; PS[1] = sc;
    for (int k = cnt; k < 64; ++k) { pair_ro[k] = 0; pair_sl[k] = 0; }
  }
  const size_t vbase = ((size_t)(b * N_ + n) * H_ + h) * 64;
  qlds[h][lane] = qbuf[vbase + lane];   // wave-local
  __syncthreads();
  const int P = PS[0], S = PS[1];

  for (int s = 0; s < S; ++s)
    Qlds[h][s][lane] = Qs[((size_t)sdepth[s] * 16384 + (size_t)(b * N_ + n) * H_ + h) * 64 + lane];
  // Qlds[h]/qlds[h]/sclds[h] are wave-local -> in-order LDS, no barrier needed

  // ---- local sliding-window attention ----
  const int w = lane & 31, half = lane >> 5;
  const int wmax = (n + 1 < 32) ? (n + 1) : 32;
  float scl = 0.f;
  if (w < wmax) {
    const float4* k4 = (const float4*)(klbuf + vbase - (size_t)w * 512 + half * 32);
    const float4* q4 = (const float4*)&qlds[h][half * 32];
#pragma unroll
    for (int e = 0; e < 8; ++e) scl += dot4(q4[e], k4[e]);
  }
  scl += __shfl_xor(scl, 32);
  scl *= 0.125f;
  float sm = (w < wmax) ? scl : -1e30f;
  float mx = sm;
#pragma unroll
  for (int o = 1; o < 32; o <<= 1) mx = fmaxf(mx, __shfl_xor(mx, o));
  float le = (w < wmax) ? __expf(sm - mx) : 0.f;
  float den = le;
#pragma unroll
  for (int o = 1; o < 32; o <<= 1) den += __shfl_xor(den, o);
  float lp = le / den;
  float local = 0.f;
  if (n >= 31) {
#pragma unroll 8
    for (int ww = 0; ww < 32; ++ww) {
      float pw = __shfl(lp, ww);
      local += pw * vlbuf[vbase - (size_t)ww * 512 + lane];
    }
  } else {
    for (int ww = 0; ww < wmax; ++ww) {
      float pw = __shfl(lp, ww);
      local += pw * vlbuf[vbase - (size_t)ww * 512 + lane];
    }
  }

  // ---- tree attention: 4 lanes per pair (64B contiguous per lane) ----
  const size_t bhbase = (size_t)(b * H_ + h) * TOTV * 64;
  float tree = 0.f;
  if (P > 0) {
    const int passes = (P + 15) >> 4;
    for (int t = 0; t < passes; ++t) {
      const int p = (t << 4) + (lane >> 2);
      const int c = lane & 3;
      float s = 0.f;
      if (p < P) {
        const float4* b4 = (const float4*)(bank + bhbase + pair_ro[p] + c * 16);
        const float4* q4 = (const float4*)&Qlds[h][pair_sl[p]][c * 16];
#pragma unroll
        for (int i = 0; i < 4; ++i) s += dot4(q4[i], b4[i]);
      }
      s += __shfl_xor(s, 1);
      s += __shfl_xor(s, 2);
      if (c == 0 && p < P) sclds[h][p] = s;
    }
    float logit = (lane < P) ? sclds[h][lane] : -1e30f;
    float tm = logit;
#pragma unroll
    for (int o = 1; o < 64; o <<= 1) tm = fmaxf(tm, __shfl_xor(tm, o));
    float te = (lane < P) ? __expf(logit - tm) : 0.f;
    float tden = te;
#pragma unroll
    for (int o = 1; o < 64; o <<= 1) tden += __shfl_xor(tden, o);
    float tw = te / tden;     // lanes >= P carry tw = 0
    const int P4 = (P + 3) & ~3;
    for (int l2 = 0; l2 < P4; l2 += 4) {
      float w0_ = __shfl(tw, l2),     w1_ = __shfl(tw, l2 + 1);
      float w2_ = __shfl(tw, l2 + 2), w3_ = __shfl(tw, l2 + 3);
      float v0 = bank[bhbase + pair_ro[l2]     + lane];
      float v1 = bank[bhbase + pair_ro[l2 + 1] + lane];
      float v2 = bank[bhbase + pair_ro[l2 + 2] + lane];
      float v3 = bank[bhbase + pair_ro[l2 + 3] + lane];
      tree += w0_ * v0 + w1_ * v1 + w2_ * v2 + w3_ * v3;
    }
  }

  // ---- gate + fused split-bf16 epilogue (A-side PAT0 [hi|lo|hi], K=512) ----
  float g = gatebuf[vbase + lane];
  float v = local + g * tree;
  unsigned short hi = f2b(v), lo = f2b(v - b2f(hi));
  const size_t m = (size_t)(b * N_ + n);
  const int k = h * 64 + lane;
  A2o[m * 1536 + k] = hi;
  A2o[m * 1536 + 512 + k] = lo;
  A2o[m * 1536 + 1024 + k] = hi;
}

// ---------------- launcher ----------------
extern "C" void kernel_launch(void* const* d_in, const int* in_sizes, int n_in,
                              void* d_out, int out_size, void* d_ws, size_t ws_size,
                              hipStream_t stream)
{
  (void)in_sizes; (void)n_in; (void)out_size; (void)ws_size;
  const float* x     = (const float*)d_in[0];
  const float* qW    = (const float*)d_in[1];
  const float* qb    = (const float*)d_in[2];
  const float* vW    = (const float*)d_in[3];
  const float* vb    = (const float*)d_in[4];
  const float* oW    = (const float*)d_in[5];
  const float* ob    = (const float*)d_in[6];
  const float* klW   = (const float*)d_in[7];
  const float* klb   = (const float*)d_in[8];
  const float* vlW   = (const float*)d_in[9];
  const float* vlb   = (const float*)d_in[10];
  const float* gW    = (const float*)d_in[11];
  const float* gb    = (const float*)d_in[12];
  const float* ddqW  = (const float*)d_in[13];
  const float* ddqT  = (const float*)d_in[14];
  const float* wfreq = (const float*)d_in[15];
  const float* wdamp = (const float*)d_in[16];
  const float* wphase= (const float*)d_in[17];
  const float* glW   = (const float*)d_in[18];
  const float* glb   = (const float*)d_in[19];
  const float* grW   = (const float*)d_in[20];
  const float* grb   = (const float*)d_in[21];
  const float* pq    = (const float*)d_in[22];
  const float* lnG   = (const float*)d_in[23];
  const float* lnB   = (const float*)d_in[24];
  const float* skA   = (const float*)d_in[25];
  const float* skW   = (const float*)d_in[26];
  const float* coup  = (const float*)d_in[27];

  float* ws = (float*)d_ws;
  float* qbuf    = ws; ws += (size_t)2048 * 512;
  float* klbuf   = ws; ws += (size_t)2048 * 512;
  float* vlbuf   = ws; ws += (size_t)2048 * 512;
  float* gatebuf = ws; ws += (size_t)2048 * 512;
  float* bank    = ws; ws += (size_t)16 * TOTV * 64;
  float* Qs      = ws; ws += (size_t)10 * 16384 * 64;
  unsigned short* A2x = (unsigned short*)ws; ws += (size_t)2048 * 1536 / 2;
  unsigned short* B2w = (unsigned short*)ws; ws += (size_t)2560 * 1536 / 2;
  unsigned short* A2q = (unsigned short*)ws; ws += (size_t)16384 * 192 / 2;
  unsigned short* B2q = (unsigned short*)ws; ws += (size_t)640 * 192 / 2;
  unsigned short* A2o = (unsigned short*)ws; ws += (size_t)2048 * 1536 / 2;
  unsigned short* B2o = (unsigned short*)ws; ws += (size_t)512 * 1536 / 2;

  prep_kernel<<<2720, 256, 0, stream>>>(x, qW, vW, klW, vlW, gW, oW, ddqW, ddqT,
                                        A2x, B2w, B2o, B2q);

  gemm_mfma<0><<<dim3(20, 16), 256, 0, stream>>>(A2x, B2w, 1536,
      qb, vb, klb, vlb, gb, qbuf, bank, klbuf, vlbuf, gatebuf,
      nullptr, nullptr, nullptr, A2q);

  gemm_mfma<1><<<dim3(5, 128), 256, 0, stream>>>(A2q, B2q, 192,
      nullptr, nullptr, nullptr, nullptr, nullptr,
      nullptr, nullptr, nullptr, nullptr, nullptr, Qs, nullptr, nullptr, nullptr);

#define LVL(DD) level4<DD><<<dim3(1024 >> DD, 2), 512, 0, stream>>>( \
      glW, glb, grW, grb, pq, lnG, lnB, skA, skW, coup, wfreq, wdamp, wphase, bank)
  LVL(1); LVL(2); LVL(3); LVL(4); LVL(5); LVL(6); LVL(7); LVL(8); LVL(9);
#undef LVL

  combine3<<<dim3(1024, 2), 512, 0, stream>>>(qbuf, klbuf, vlbuf, gatebuf, bank, Qs, A2o);

  gemm_mfma<2><<<dim3(4, 16), 256, 0, stream>>>(A2o, B2o, 1536,
      nullptr, nullptr, nullptr, nullptr, nullptr,
      nullptr, nullptr, nullptr, nullptr, nullptr, nullptr,
      (float*)d_out, ob, nullptr);
}

// Round 6
// 426.168 us; speedup vs baseline: 1.3996x; 1.3959x over previous
//
#include <hip/hip_runtime.h>
#include <math.h>

#define B_ 2
#define N_ 1024
#define H_ 8
#define TOTV 5104   // compact bank vectors per (b,h)

typedef __attribute__((ext_vector_type(8))) short bf16x8;
typedef __attribute__((ext_vector_type(4))) float f32x4;

__device__ __constant__ int VBASE[11] = {0,1024,2048,3072,4096,4608,4864,4992,5056,5088,5104};

constexpr int vbase_of(int d) {
  int v = 0;
  for (int i = 0; i < d; ++i) v += (1024 >> i) * ((i >= 3) ? 8 : (1 << i));
  return v;
}

// ---------------- helpers ----------------
__device__ __forceinline__ float wsum(float v) {
  v += __shfl_xor(v, 1);  v += __shfl_xor(v, 2);  v += __shfl_xor(v, 4);
  v += __shfl_xor(v, 8);  v += __shfl_xor(v, 16); v += __shfl_xor(v, 32);
  return v;
}
__device__ __forceinline__ float sigmoidf_(float x) { return 1.f / (1.f + __expf(-x)); }
__device__ __forceinline__ unsigned short f2b(float f) {
  unsigned u = __float_as_uint(f);
  return (unsigned short)((u + 0x7FFFu + ((u >> 16) & 1u)) >> 16);
}
__device__ __forceinline__ float b2f(unsigned short h) {
  return __uint_as_float(((unsigned)h) << 16);
}
__device__ __forceinline__ float dot4(float4 a, float4 b) {
  return a.x*b.x + a.y*b.y + a.z*b.z + a.w*b.w;
}
// readlane with compile-time lane: uniform broadcast, no LDS (vs __shfl -> ds_bpermute)
__device__ __forceinline__ float rl(float v, int l) {
  return __uint_as_float(__builtin_amdgcn_readlane(__float_as_uint(v), l));
}

// ---------------- fused prep: splitA(x) | splitB5(w) | splitB(oW) | build_w2b ----------------
__global__ void prep_kernel(const float* __restrict__ x,
                            const float* __restrict__ w0, const float* __restrict__ w1,
                            const float* __restrict__ w2, const float* __restrict__ w3,
                            const float* __restrict__ w4, const float* __restrict__ oW,
                            const float* __restrict__ ddqW, const float* __restrict__ ddqT,
                            unsigned short* __restrict__ A2x, unsigned short* __restrict__ B2w,
                            unsigned short* __restrict__ B2o, unsigned short* __restrict__ B2q)
{
  const int bx = blockIdx.x;
  const int tid = threadIdx.x;
  if (bx < 1024) {
    int i = (bx * 256 + tid) * 4;
    int m = i >> 9, k = i & 511;
    float4 f = *(const float4*)(x + i);
    float fv[4] = {f.x, f.y, f.z, f.w};
    unsigned short h[4], l[4];
#pragma unroll
    for (int j = 0; j < 4; ++j) { h[j] = f2b(fv[j]); l[j] = f2b(fv[j] - b2f(h[j])); }
    size_t base = (size_t)m * 1536;
    ushort4 hv = {h[0], h[1], h[2], h[3]};
    ushort4 lv = {l[0], l[1], l[2], l[3]};
    *(ushort4*)(A2x + base + k) = hv;
    *(ushort4*)(A2x + base + 512 + k) = lv;
    *(ushort4*)(A2x + base + 1024 + k) = hv;
  } else if (bx < 2304) {
    int i = ((bx - 1024) * 256 + tid) * 4;
    int nrow = i >> 9, k = i & 511;
    int sel = nrow >> 9;
    const float* w = sel == 0 ? w0 : sel == 1 ? w1 : sel == 2 ? w2 : sel == 3 ? w3 : w4;
    float4 f = *(const float4*)(w + (size_t)(nrow & 511) * 512 + k);
    float fv[4] = {f.x, f.y, f.z, f.w};
    unsigned short h[4], l[4];
#pragma unroll
    for (int j = 0; j < 4; ++j) { h[j] = f2b(fv[j]); l[j] = f2b(fv[j] - b2f(h[j])); }
    size_t base = (size_t)nrow * 1536;
    ushort4 hv = {h[0], h[1], h[2], h[3]};
    ushort4 lv = {l[0], l[1], l[2], l[3]};
    *(ushort4*)(B2w + base + k) = hv;
    *(ushort4*)(B2w + base + 512 + k) = hv;
    *(ushort4*)(B2w + base + 1024 + k) = lv;
  } else if (bx < 2560) {
    int i = ((bx - 2304) * 256 + tid) * 4;
    int m = i >> 9, k = i & 511;
    float4 f = *(const float4*)(oW + i);
    float fv[4] = {f.x, f.y, f.z, f.w};
    unsigned short h[4], l[4];
#pragma unroll
    for (int j = 0; j < 4; ++j) { h[j] = f2b(fv[j]); l[j] = f2b(fv[j] - b2f(h[j])); }
    size_t base = (size_t)m * 1536;
    ushort4 hv = {h[0], h[1], h[2], h[3]};
    ushort4 lv = {l[0], l[1], l[2], l[3]};
    *(ushort4*)(B2o + base + k) = hv;
    *(ushort4*)(B2o + base + 512 + k) = hv;
    *(ushort4*)(B2o + base + 1024 + k) = lv;
  } else {
    int i = (bx - 2560) * 256 + tid;
    int row = i >> 6, e = i & 63;
    int p = row >> 6, o = row & 63;
    float t = ddqT[p];
    float sp = log1pf(__expf(t));
    float scd = 1.f / ((sp + 1e-6f) * 8.0f);
    float w = (ddqW[(size_t)(p * 64 + o) * 64 + e] + (o == e ? 1.f : 0.f)) * scd;
    unsigned short h = f2b(w);
    unsigned short l = f2b(w - b2f(h));
    size_t base = (size_t)row * 192;
    B2q[base + e] = h; B2q[base + 64 + e] = h; B2q[base + 128 + e] = l;
  }
}

// ---------------- MFMA GEMM ----------------
template<int MODE>
__global__ __launch_bounds__(256)
void gemm_mfma(const unsigned short* __restrict__ A2, const unsigned short* __restrict__ B2,
               int K3,
               const float* __restrict__ bq, const float* __restrict__ bv,
               const float* __restrict__ bkl, const float* __restrict__ bvl,
               const float* __restrict__ bgt,
               float* __restrict__ qbuf, float* __restrict__ bank,
               float* __restrict__ klbuf, float* __restrict__ vlbuf,
               float* __restrict__ gatebuf, float* __restrict__ Qs,
               float* __restrict__ oout, const float* __restrict__ ob,
               unsigned short* __restrict__ A2q)
{
  __shared__ __align__(16) unsigned short Asb[128 * 40];
  __shared__ __align__(16) unsigned short Bsb[128 * 40];
  const int tid = threadIdx.x;
  const int wave = tid >> 6, lane = tid & 63;
  const int wr = wave >> 1, wc = wave & 1;
  const int row0 = blockIdx.y * 128, col0 = blockIdx.x * 128;

  f32x4 acc[4][4];
#pragma unroll
  for (int i = 0; i < 4; ++i)
#pragma unroll
    for (int j = 0; j < 4; ++j) acc[i][j] = (f32x4){0.f, 0.f, 0.f, 0.f};

  const int srow = tid >> 1;
  const int shalf = tid & 1;
  const unsigned short* agp = A2 + (size_t)(row0 + srow) * K3 + shalf * 16;
  const unsigned short* bgp = B2 + (size_t)(col0 + srow) * K3 + shalf * 16;
  const int lrow = lane & 15, kslot = lane >> 4;

  for (int kt = 0; kt < K3; kt += 32) {
    int4 a0 = *(const int4*)(agp + kt);
    int4 a1 = *(const int4*)(agp + kt + 8);
    int4 b0 = *(const int4*)(bgp + kt);
    int4 b1 = *(const int4*)(bgp + kt + 8);
    __syncthreads();
    *(int4*)(Asb + srow * 40 + shalf * 16) = a0;
    *(int4*)(Asb + srow * 40 + shalf * 16 + 8) = a1;
    *(int4*)(Bsb + srow * 40 + shalf * 16) = b0;
    *(int4*)(Bsb + srow * 40 + shalf * 16 + 8) = b1;
    __syncthreads();
    bf16x8 af[4], bf[4];
#pragma unroll
    for (int m = 0; m < 4; ++m)
      af[m] = *(const bf16x8*)(Asb + (wr * 64 + m * 16 + lrow) * 40 + kslot * 8);
#pragma unroll
    for (int n = 0; n < 4; ++n)
      bf[n] = *(const bf16x8*)(Bsb + (wc * 64 + n * 16 + lrow) * 40 + kslot * 8);
#pragma unroll
    for (int m = 0; m < 4; ++m)
#pragma unroll
      for (int n = 0; n < 4; ++n)
        acc[m][n] = __builtin_amdgcn_mfma_f32_16x16x32_bf16(af[m], bf[n], acc[m][n], 0, 0, 0);
  }

#pragma unroll
  for (int m = 0; m < 4; ++m)
#pragma unroll
    for (int n = 0; n < 4; ++n)
#pragma unroll
      for (int r = 0; r < 4; ++r) {
        const int row = row0 + wr * 64 + m * 16 + (lane >> 4) * 4 + r;
        const int col = col0 + wc * 64 + n * 16 + (lane & 15);
        float v = acc[m][n][r];
        if (MODE == 0) {
          const int sel = col >> 9;
          const int c = col & 511;
          const int bb = row >> 10, nn = row & 1023;
          if (sel == 0) {
            float vv = v + bq[c];
            qbuf[(size_t)row * 512 + c] = vv;
            unsigned short hi = f2b(vv), lo = f2b(vv - b2f(hi));
            size_t mq = (size_t)row * 8 + (c >> 6);
            int kq = c & 63;
            A2q[mq * 192 + kq] = hi;
            A2q[mq * 192 + 64 + kq] = lo;
            A2q[mq * 192 + 128 + kq] = hi;
          } else if (sel == 1) {
            bank[((size_t)(bb * 8 + (c >> 6)) * TOTV + nn) * 64 + (c & 63)] = v + bv[c];
          } else if (sel == 2) {
            klbuf[(size_t)row * 512 + c] = v + bkl[c];
          } else if (sel == 3) {
            vlbuf[(size_t)row * 512 + c] = v + bvl[c];
          } else {
            gatebuf[(size_t)row * 512 + c] = sigmoidf_(v + bgt[c]);
          }
        } else if (MODE == 1) {
          Qs[((size_t)(col >> 6) * 16384 + row) * 64 + (col & 63)] = v;
        } else {
          oout[(size_t)row * 512 + col] = v + ob[col];
        }
      }
}

// ---------------- tree level v5: transposed+packed LDS weights, readlane gin broadcast ----------------
template<int D, int NPB>
__global__ __launch_bounds__(512)
void level5(const float* __restrict__ glW, const float* __restrict__ glb,
            const float* __restrict__ grW, const float* __restrict__ grb,
            const float* __restrict__ pq, const float* __restrict__ lnG,
            const float* __restrict__ lnB, const float* __restrict__ skA,
            const float* __restrict__ skW, const float* __restrict__ coup,
            const float* __restrict__ wfreq, const float* __restrict__ wdamp,
            const float* __restrict__ wphase, float* __restrict__ bank)
{
  constexpr int KPREV = ((D - 1) >= 3) ? 8 : (1 << (D - 1));
  constexpr int SLOTS = 2 * KPREV;
  constexpr int KP = (D >= 3) ? 8 : (1 << D);
  constexpr bool TP = (D >= 3);
  constexpr int VB_PREV = vbase_of(D - 1);
  constexpr int VB_CUR  = vbase_of(D);

  // (gl,gr) interleaved float2 per [e][o]: lane o reads b64 at 2*lane -> conflict-free
  __shared__ __align__(8)  float wpk[128 * 130];
  __shared__ float sklds[64 * 65];          // [e][o], bank (e+o)%32 -> free
  __shared__ float parlds[8][KP][64];
  __shared__ __align__(16) float slds[TP ? 8 * SLOTS * 68 : 1];
  __shared__ float wlds[TP ? 8 * KP * 17 : 1];
  __shared__ __align__(16) float pqlds[TP ? KP * 68 : 1];

  const int tid = threadIdx.x;
  const int h = tid >> 6, lane = tid & 63;
  const int b = blockIdx.y;

  // ---- stage weights transposed (coalesced global reads) ----
  for (int i = tid; i < 64 * 128; i += 512) {
    int o = i >> 7, e = i & 127;
    wpk[e * 130 + 2 * o]     = glW[(size_t)D * 8192 + i];
    wpk[e * 130 + 2 * o + 1] = grW[(size_t)D * 8192 + i];
  }
  for (int i = tid; i < 64 * 64; i += 512) {
    int o = i >> 6, e = i & 63;
    sklds[e * 65 + o] = skW[(size_t)D * 4096 + i];
  }
  if constexpr (TP) {
    for (int i = tid; i < KP * 64; i += 512)
      pqlds[(i >> 6) * 68 + (i & 63)] = pq[(size_t)D * 512 + i];
  }
  __syncthreads();

  const float alpha = log1pf(__expf(wdamp[h]));
  const float dec = __expf(-alpha);
  const float ang = wfreq[h] + wphase[h] + (float)D * 0.78539816339744831f;
  const float pr  = dec * cosf(ang);
  const float pim = dec * sinf(ang);
  const float glbv = glb[D * 64 + lane], grbv = grb[D * 64 + lane];
  const float lnGv = lnG[D * 64 + lane], lnBv = lnB[D * 64 + lane];
  const float sig_sk = sigmoidf_(skA[D]);
  float cw[8];
  float cmx = -1e30f;
#pragma unroll
  for (int j = 0; j < 8; ++j) { cw[j] = coup[(size_t)(D * 8 + h) * 8 + j]; cmx = fmaxf(cmx, cw[j]); }
  float cs = 0.f;
#pragma unroll
  for (int j = 0; j < 8; ++j) { cw[j] = __expf(cw[j] - cmx); cs += cw[j]; }
  const float cinv = 1.f / cs;

  const size_t bh = (size_t)(b * H_ + h);
  const float* prevb = bank + (bh * TOTV + VB_PREV) * 64;
  float* curb = bank + (bh * TOTV + VB_CUR) * 64;

  for (int nn = 0; nn < NPB; ++nn) {
    const int node = blockIdx.x * NPB + nn;
    float par[KP];
    float fL[KPREV], rot[KPREV];
    {
      float lm = 0.f, rm = 0.f;
#pragma unroll
      for (int k = 0; k < KPREV; ++k) {
        fL[k] = prevb[(size_t)((2 * node) * KPREV + k) * 64 + lane];
        float fr = prevb[(size_t)((2 * node + 1) * KPREV + k) * 64 + lane];
        float partner = __shfl_xor(fr, 32);
        rot[k] = (lane < 32) ? (pr * fr - pim * partner) : (pim * partner + pr * fr);
        lm += fL[k]; rm += rot[k];
      }
      lm *= (1.f / KPREV); rm *= (1.f / KPREV);

      // ---- gates: g broadcast via readlane (const lane), weights from conflict-free LDS ----
      float gl = glbv, gr = grbv, sk = 0.f;
#pragma unroll
      for (int e = 0; e < 64; ++e) {
        float g = rl(lm, e);
        float2 w2 = *(const float2*)&wpk[e * 130 + 2 * lane];
        gl += g * w2.x;
        gr += g * w2.y;
        sk += g * sklds[e * 65 + lane];
      }
#pragma unroll
      for (int e = 0; e < 64; ++e) {
        float g = rl(rm, e);
        float2 w2 = *(const float2*)&wpk[(64 + e) * 130 + 2 * lane];
        gl += g * w2.x;
        gr += g * w2.y;
      }
      gl = sigmoidf_(gl); gr = sigmoidf_(gr);

      float slot[SLOTS];
#pragma unroll
      for (int k = 0; k < KPREV; ++k) { slot[k] = fL[k] * gl; slot[KPREV + k] = rot[k] * gr; }

      if constexpr (!TP) {
        float pqv[KP];
#pragma unroll
        for (int qi = 0; qi < KP; ++qi) pqv[qi] = pq[(size_t)(D * 8 + qi) * 64 + lane];
#pragma unroll
        for (int qi = 0; qi < KP; ++qi) {
          float lg[SLOTS];
          float mx = -1e30f;
#pragma unroll
          for (int kk = 0; kk < SLOTS; ++kk) {
            lg[kk] = wsum(pqv[qi] * slot[kk]) * 0.125f;
            mx = fmaxf(mx, lg[kk]);
          }
          float den = 0.f, pv = 0.f;
#pragma unroll
          for (int kk = 0; kk < SLOTS; ++kk) {
            float w = __expf(lg[kk] - mx);
            den += w; pv += w * slot[kk];
          }
          par[qi] = pv / den;
        }
      } else {
        float* sl = &slds[h * SLOTS * 68];
#pragma unroll
        for (int kk = 0; kk < SLOTS; ++kk) sl[kk * 68 + lane] = slot[kk];
        constexpr int PAIRS = KP * SLOTS;   // 64 (D=3) or 128 (D>=4)
        const int kk0 = lane & (SLOTS - 1);
        const int qg  = lane / SLOTS;
        float s0 = 0.f, s1 = 0.f;
        {
          const float4* sv = (const float4*)&sl[kk0 * 68];
          const float4* q0 = (const float4*)&pqlds[qg * 68];
#pragma unroll
          for (int e = 0; e < 16; ++e) s0 += dot4(q0[e], sv[e]);
          if constexpr (PAIRS == 128) {
            const float4* q1 = (const float4*)&pqlds[(qg + 4) * 68];
#pragma unroll
            for (int e = 0; e < 16; ++e) s1 += dot4(q1[e], sv[e]);
          }
        }
        s0 *= 0.125f; s1 *= 0.125f;
        float m0 = s0, m1 = s1;
#pragma unroll
        for (int o = 1; o < SLOTS; o <<= 1) {
          m0 = fmaxf(m0, __shfl_xor(m0, o));
          if constexpr (PAIRS == 128) m1 = fmaxf(m1, __shfl_xor(m1, o));
        }
        float e0 = __expf(s0 - m0), e1 = (PAIRS == 128) ? __expf(s1 - m1) : 0.f;
        float d0 = e0, d1 = e1;
#pragma unroll
        for (int o = 1; o < SLOTS; o <<= 1) {
          d0 += __shfl_xor(d0, o);
          if constexpr (PAIRS == 128) d1 += __shfl_xor(d1, o);
        }
        float* wld = &wlds[h * KP * 17];
        wld[qg * 17 + kk0] = e0 / d0;
        if constexpr (PAIRS == 128) wld[(qg + 4) * 17 + kk0] = e1 / d1;
#pragma unroll
        for (int qi = 0; qi < KP; ++qi) {
          float acc2 = 0.f;
#pragma unroll
          for (int kk = 0; kk < SLOTS; ++kk) acc2 += wld[qi * 17 + kk] * slot[kk];
          par[qi] = acc2;
        }
      }

      // LN + skip
#pragma unroll
      for (int qi = 0; qi < KP; ++qi) {
        float mu = wsum(par[qi]) * (1.f / 64.f);
        float dv = par[qi] - mu;
        float var = wsum(dv * dv) * (1.f / 64.f);
        float nv = dv * rsqrtf(var + 1e-5f);
        par[qi] = nv * lnGv + lnBv + sig_sk * sk;
        parlds[h][qi][lane] = par[qi];
      }
    }
    __syncthreads();
#pragma unroll
    for (int qi = 0; qi < KP; ++qi) {
      float o = 0.f;
#pragma unroll
      for (int j = 0; j < 8; ++j) o += cw[j] * parlds[j][qi][lane];
      curb[(size_t)(node * KP + qi) * 64 + lane] = o * cinv;
    }
    __syncthreads();
  }
}

// ---------------- combine v3: XCD swizzle + 4-lane score gather + unrolled PV ----------------
__global__ __launch_bounds__(512)
void combine3(const float* __restrict__ qbuf, const float* __restrict__ klbuf,
              const float* __restrict__ vlbuf, const float* __restrict__ gatebuf,
              const float* __restrict__ bank, const float* __restrict__ Qs,
              unsigned short* __restrict__ A2o)
{
  const int flat = blockIdx.y * 1024 + blockIdx.x;
  const int swz = (flat & 7) * 256 + (flat >> 3);
  const int n = swz & 1023;
  const int b = swz >> 10;
  const int h = threadIdx.x >> 6;
  const int lane = threadIdx.x & 63;
  __shared__ int pair_ro[64];
  __shared__ int pair_sl[64];
  __shared__ int sdepth[16];
  __shared__ int PS[2];
  __shared__ __align__(16) float Qlds[8][10][68];
  __shared__ __align__(16) float qlds[8][64];
  __shared__ float sclds[8][64];

  if (threadIdx.x == 0) {
    int l = 2048, r = 2048 + n;
    int cnt = 0, sc = 0;
    while (l < r) {
      if (l & 1) {
        int m = l++;
        int j = 31 - __clz(m);
        int d = 11 - j;
        int local = m - (1 << j);
        int kv = (d >= 3) ? 8 : (1 << d);
        sdepth[sc] = d;
        int vb = VBASE[d] + local * kv;
        for (int k = 0; k < kv; ++k) { pair_ro[cnt] = (vb + k) * 64; pair_sl[cnt] = sc; ++cnt; }
        ++sc;
      }
      if (r & 1) {
        int m = --r;
        int j = 31 - __clz(m);
        int d = 11 - j;
        int local = m - (1 << j);
        int kv = (d >= 3) ? 8 : (1 << d);
        sdepth[sc] = d;
        int vb = VBASE[d] + local * kv;
        for (int k = 0; k < kv; ++k) { pair_ro[cnt] = (vb + k) * 64; pair_sl[cnt] = sc; ++cnt; }
        ++sc;
      }
      l >>= 1; r >>= 1;
    }
    PS[0] = cnt; PS[1] = sc;
    for (int k = cnt; k < 64; ++k) { pair_ro[k] = 0; pair_sl[k] = 0; }
  }
  const size_t vbase = ((size_t)(b * N_ + n) * H_ + h) * 64;
  qlds[h][lane] = qbuf[vbase + lane];   // wave-local
  __syncthreads();
  const int P = PS[0], S = PS[1];

  for (int s = 0; s < S; ++s)
    Qlds[h][s][lane] = Qs[((size_t)sdepth[s] * 16384 + (size_t)(b * N_ + n) * H_ + h) * 64 + lane];
  // Qlds[h]/qlds[h]/sclds[h] are wave-local -> no barrier needed

  // ---- local sliding-window attention ----
  const int w = lane & 31, half = lane >> 5;
  const int wmax = (n + 1 < 32) ? (n + 1) : 32;
  float scl = 0.f;
  if (w < wmax) {
    const float4* k4 = (const float4*)(klbuf + vbase - (size_t)w * 512 + half * 32);
    const float4* q4 = (const float4*)&qlds[h][half * 32];
#pragma unroll
    for (int e = 0; e < 8; ++e) scl += dot4(q4[e], k4[e]);
  }
  scl += __shfl_xor(scl, 32);
  scl *= 0.125f;
  float sm = (w < wmax) ? scl : -1e30f;
  float mx = sm;
#pragma unroll
  for (int o = 1; o < 32; o <<= 1) mx = fmaxf(mx, __shfl_xor(mx, o));
  float le = (w < wmax) ? __expf(sm - mx) : 0.f;
  float den = le;
#pragma unroll
  for (int o = 1; o < 32; o <<= 1) den += __shfl_xor(den, o);
  float lp = le / den;
  float local = 0.f;
  if (n >= 31) {
#pragma unroll 8
    for (int ww = 0; ww < 32; ++ww) {
      float pw = __shfl(lp, ww);
      local += pw * vlbuf[vbase - (size_t)ww * 512 + lane];
    }
  } else {
    for (int ww = 0; ww < wmax; ++ww) {
      float pw = __shfl(lp, ww);
      local += pw * vlbuf[vbase - (size_t)ww * 512 + lane];
    }
  }

  // ---- tree attention: 4 lanes per pair ----
  const size_t bhbase = (size_t)(b * H_ + h) * TOTV * 64;
  float tree = 0.f;
  if (P > 0) {
    const int passes = (P + 15) >> 4;
    for (int t = 0; t < passes; ++t) {
      const int p = (t << 4) + (lane >> 2);
      const int c = lane & 3;
      float s = 0.f;
      if (p < P) {
        const float4* b4 = (const float4*)(bank + bhbase + pair_ro[p] + c * 16);
        const float4* q4 = (const float4*)&Qlds[h][pair_sl[p]][c * 16];
#pragma unroll
        for (int i = 0; i < 4; ++i) s += dot4(q4[i], b4[i]);
      }
      s += __shfl_xor(s, 1);
      s += __shfl_xor(s, 2);
      if (c == 0 && p < P) sclds[h][p] = s;
    }
    float logit = (lane < P) ? sclds[h][lane] : -1e30f;
    float tm = logit;
#pragma unroll
    for (int o = 1; o < 64; o <<= 1) tm = fmaxf(tm, __shfl_xor(tm, o));
    float te = (lane < P) ? __expf(logit - tm) : 0.f;
    float tden = te;
#pragma unroll
    for (int o = 1; o < 64; o <<= 1) tden += __shfl_xor(tden, o);
    float tw = te / tden;
    const int P4 = (P + 3) & ~3;
    for (int l2 = 0; l2 < P4; l2 += 4) {
      float w0_ = __shfl(tw, l2),     w1_ = __shfl(tw, l2 + 1);
      float w2_ = __shfl(tw, l2 + 2), w3_ = __shfl(tw, l2 + 3);
      float v0 = bank[bhbase + pair_ro[l2]     + lane];
      float v1 = bank[bhbase + pair_ro[l2 + 1] + lane];
      float v2 = bank[bhbase + pair_ro[l2 + 2] + lane];
      float v3 = bank[bhbase + pair_ro[l2 + 3] + lane];
      tree += w0_ * v0 + w1_ * v1 + w2_ * v2 + w3_ * v3;
    }
  }

  float g = gatebuf[vbase + lane];
  float v = local + g * tree;
  unsigned short hi = f2b(v), lo = f2b(v - b2f(hi));
  const size_t m = (size_t)(b * N_ + n);
  const int k = h * 64 + lane;
  A2o[m * 1536 + k] = hi;
  A2o[m * 1536 + 512 + k] = lo;
  A2o[m * 1536 + 1024 + k] = hi;
}

// ---------------- launcher ----------------
extern "C" void kernel_launch(void* const* d_in, const int* in_sizes, int n_in,
                              void* d_out, int out_size, void* d_ws, size_t ws_size,
                              hipStream_t stream)
{
  (void)in_sizes; (void)n_in; (void)out_size; (void)ws_size;
  const float* x     = (const float*)d_in[0];
  const float* qW    = (const float*)d_in[1];
  const float* qb    = (const float*)d_in[2];
  const float* vW    = (const float*)d_in[3];
  const float* vb    = (const float*)d_in[4];
  const float* oW    = (const float*)d_in[5];
  const float* ob    = (const float*)d_in[6];
  const float* klW   = (const float*)d_in[7];
  const float* klb   = (const float*)d_in[8];
  const float* vlW   = (const float*)d_in[9];
  const float* vlb   = (const float*)d_in[10];
  const float* gW    = (const float*)d_in[11];
  const float* gb    = (const float*)d_in[12];
  const float* ddqW  = (const float*)d_in[13];
  const float* ddqT  = (const float*)d_in[14];
  const float* wfreq = (const float*)d_in[15];
  const float* wdamp = (const float*)d_in[16];
  const float* wphase= (const float*)d_in[17];
  const float* glW   = (const float*)d_in[18];
  const float* glb   = (const float*)d_in[19];
  const float* grW   = (const float*)d_in[20];
  const float* grb   = (const float*)d_in[21];
  const float* pq    = (const float*)d_in[22];
  const float* lnG   = (const float*)d_in[23];
  const float* lnB   = (const float*)d_in[24];
  const float* skA   = (const float*)d_in[25];
  const float* skW   = (const float*)d_in[26];
  const float* coup  = (const float*)d_in[27];

  float* ws = (float*)d_ws;
  float* qbuf    = ws; ws += (size_t)2048 * 512;
  float* klbuf   = ws; ws += (size_t)2048 * 512;
  float* vlbuf   = ws; ws += (size_t)2048 * 512;
  float* gatebuf = ws; ws += (size_t)2048 * 512;
  float* bank    = ws; ws += (size_t)16 * TOTV * 64;
  float* Qs      = ws; ws += (size_t)10 * 16384 * 64;
  unsigned short* A2x = (unsigned short*)ws; ws += (size_t)2048 * 1536 / 2;
  unsigned short* B2w = (unsigned short*)ws; ws += (size_t)2560 * 1536 / 2;
  unsigned short* A2q = (unsigned short*)ws; ws += (size_t)16384 * 192 / 2;
  unsigned short* B2q = (unsigned short*)ws; ws += (size_t)640 * 192 / 2;
  unsigned short* A2o = (unsigned short*)ws; ws += (size_t)2048 * 1536 / 2;
  unsigned short* B2o = (unsigned short*)ws; ws += (size_t)512 * 1536 / 2;

  prep_kernel<<<2720, 256, 0, stream>>>(x, qW, vW, klW, vlW, gW, oW, ddqW, ddqT,
                                        A2x, B2w, B2o, B2q);

  gemm_mfma<0><<<dim3(20, 16), 256, 0, stream>>>(A2x, B2w, 1536,
      qb, vb, klb, vlb, gb, qbuf, bank, klbuf, vlbuf, gatebuf,
      nullptr, nullptr, nullptr, A2q);

  gemm_mfma<1><<<dim3(5, 128), 256, 0, stream>>>(A2q, B2q, 192,
      nullptr, nullptr, nullptr, nullptr, nullptr,
      nullptr, nullptr, nullptr, nullptr, nullptr, Qs, nullptr, nullptr, nullptr);

#define LVL(DD, NPB) level5<DD, NPB><<<dim3((1024 >> DD) / NPB, 2), 512, 0, stream>>>( \
      glW, glb, grW, grb, pq, lnG, lnB, skA, skW, coup, wfreq, wdamp, wphase, bank)
  LVL(1, 4); LVL(2, 2); LVL(3, 1); LVL(4, 1); LVL(5, 1);
  LVL(6, 1); LVL(7, 1); LVL(8, 1); LVL(9, 1);
#undef LVL

  combine3<<<dim3(1024, 2), 512, 0, stream>>>(qbuf, klbuf, vlbuf, gatebuf, bank, Qs, A2o);

  gemm_mfma<2><<<dim3(4, 16), 256, 0, stream>>>(A2o, B2o, 1536,
      nullptr, nullptr, nullptr, nullptr, nullptr,
      nullptr, nullptr, nullptr, nullptr, nullptr, nullptr,
      (float*)d_out, ob, nullptr);
}

// Round 7
// 388.228 us; speedup vs baseline: 1.5364x; 1.0977x over previous
//
#include <hip/hip_runtime.h>
#include <math.h>

#define B_ 2
#define N_ 1024
#define H_ 8
#define TOTV 5104   // compact bank vectors per (b,h)

typedef __attribute__((ext_vector_type(8))) short bf16x8;
typedef __attribute__((ext_vector_type(4))) float f32x4;

__device__ __constant__ int VBASE[11] = {0,1024,2048,3072,4096,4608,4864,4992,5056,5088,5104};

constexpr int vbase_of(int d) {
  int v = 0;
  for (int i = 0; i < d; ++i) v += (1024 >> i) * ((i >= 3) ? 8 : (1 << i));
  return v;
}

// ---------------- helpers ----------------
__device__ __forceinline__ float wsum(float v) {
  v += __shfl_xor(v, 1);  v += __shfl_xor(v, 2);  v += __shfl_xor(v, 4);
  v += __shfl_xor(v, 8);  v += __shfl_xor(v, 16); v += __shfl_xor(v, 32);
  return v;
}
__device__ __forceinline__ float sigmoidf_(float x) { return 1.f / (1.f + __expf(-x)); }
__device__ __forceinline__ unsigned short f2b(float f) {
  unsigned u = __float_as_uint(f);
  return (unsigned short)((u + 0x7FFFu + ((u >> 16) & 1u)) >> 16);
}
__device__ __forceinline__ float b2f(unsigned short h) {
  return __uint_as_float(((unsigned)h) << 16);
}
__device__ __forceinline__ float dot4(float4 a, float4 b) {
  return a.x*b.x + a.y*b.y + a.z*b.z + a.w*b.w;
}
__device__ __forceinline__ float rl(float v, int l) {
  return __uint_as_float(__builtin_amdgcn_readlane(__float_as_uint(v), l));
}
// async global->LDS, 16B per lane; LDS dest = wave-uniform base + lane*16
__device__ __forceinline__ void gl16(const unsigned short* g, unsigned short* l) {
  __builtin_amdgcn_global_load_lds(
      (const __attribute__((address_space(1))) unsigned int*)g,
      (__attribute__((address_space(3))) unsigned int*)l, 16, 0, 0);
}

// ---------------- fused prep: splitA(x) | splitB5(w) | splitB(oW) | build_w2b ----------------
__global__ void prep_kernel(const float* __restrict__ x,
                            const float* __restrict__ w0, const float* __restrict__ w1,
                            const float* __restrict__ w2, const float* __restrict__ w3,
                            const float* __restrict__ w4, const float* __restrict__ oW,
                            const float* __restrict__ ddqW, const float* __restrict__ ddqT,
                            unsigned short* __restrict__ A2x, unsigned short* __restrict__ B2w,
                            unsigned short* __restrict__ B2o, unsigned short* __restrict__ B2q)
{
  const int bx = blockIdx.x;
  const int tid = threadIdx.x;
  if (bx < 1024) {
    int i = (bx * 256 + tid) * 4;
    int m = i >> 9, k = i & 511;
    float4 f = *(const float4*)(x + i);
    float fv[4] = {f.x, f.y, f.z, f.w};
    unsigned short h[4], l[4];
#pragma unroll
    for (int j = 0; j < 4; ++j) { h[j] = f2b(fv[j]); l[j] = f2b(fv[j] - b2f(h[j])); }
    size_t base = (size_t)m * 1536;
    ushort4 hv = {h[0], h[1], h[2], h[3]};
    ushort4 lv = {l[0], l[1], l[2], l[3]};
    *(ushort4*)(A2x + base + k) = hv;
    *(ushort4*)(A2x + base + 512 + k) = lv;
    *(ushort4*)(A2x + base + 1024 + k) = hv;
  } else if (bx < 2304) {
    int i = ((bx - 1024) * 256 + tid) * 4;
    int nrow = i >> 9, k = i & 511;
    int sel = nrow >> 9;
    const float* w = sel == 0 ? w0 : sel == 1 ? w1 : sel == 2 ? w2 : sel == 3 ? w3 : w4;
    float4 f = *(const float4*)(w + (size_t)(nrow & 511) * 512 + k);
    float fv[4] = {f.x, f.y, f.z, f.w};
    unsigned short h[4], l[4];
#pragma unroll
    for (int j = 0; j < 4; ++j) { h[j] = f2b(fv[j]); l[j] = f2b(fv[j] - b2f(h[j])); }
    size_t base = (size_t)nrow * 1536;
    ushort4 hv = {h[0], h[1], h[2], h[3]};
    ushort4 lv = {l[0], l[1], l[2], l[3]};
    *(ushort4*)(B2w + base + k) = hv;
    *(ushort4*)(B2w + base + 512 + k) = hv;
    *(ushort4*)(B2w + base + 1024 + k) = lv;
  } else if (bx < 2560) {
    int i = ((bx - 2304) * 256 + tid) * 4;
    int m = i >> 9, k = i & 511;
    float4 f = *(const float4*)(oW + i);
    float fv[4] = {f.x, f.y, f.z, f.w};
    unsigned short h[4], l[4];
#pragma unroll
    for (int j = 0; j < 4; ++j) { h[j] = f2b(fv[j]); l[j] = f2b(fv[j] - b2f(h[j])); }
    size_t base = (size_t)m * 1536;
    ushort4 hv = {h[0], h[1], h[2], h[3]};
    ushort4 lv = {l[0], l[1], l[2], l[3]};
    *(ushort4*)(B2o + base + k) = hv;
    *(ushort4*)(B2o + base + 512 + k) = hv;
    *(ushort4*)(B2o + base + 1024 + k) = lv;
  } else {
    int i = (bx - 2560) * 256 + tid;
    int row = i >> 6, e = i & 63;
    int p = row >> 6, o = row & 63;
    float t = ddqT[p];
    float sp = log1pf(__expf(t));
    float scd = 1.f / ((sp + 1e-6f) * 8.0f);
    float w = (ddqW[(size_t)(p * 64 + o) * 64 + e] + (o == e ? 1.f : 0.f)) * scd;
    unsigned short h = f2b(w);
    unsigned short l = f2b(w - b2f(h));
    size_t base = (size_t)row * 192;
    B2q[base + e] = h; B2q[base + 64 + e] = h; B2q[base + 128 + e] = l;
  }
}

// ---------------- MFMA GEMM v2: global_load_lds + swizzled LDS, BMx64 tiles ----------------
// LDS slot (row, j) holds k-slot j ^ ((row>>1)&3); read fragment (row,kslot) at
// j = kslot ^ ((row>>1)&3) -> every 8 consecutive lanes cover all 32 banks (conflict-free).
template<int MODE, int BM>
__global__ __launch_bounds__(256)
void gemm_mfma(const unsigned short* __restrict__ A2, const unsigned short* __restrict__ B2,
               const int K3,
               const float* __restrict__ bq, const float* __restrict__ bv,
               const float* __restrict__ bkl, const float* __restrict__ bvl,
               const float* __restrict__ bgt,
               float* __restrict__ qbuf, float* __restrict__ bank,
               float* __restrict__ klbuf, float* __restrict__ vlbuf,
               float* __restrict__ gatebuf, float* __restrict__ Qs,
               float* __restrict__ oout, const float* __restrict__ ob,
               unsigned short* __restrict__ A2q)
{
  constexpr int MREP = BM / 32;                 // 4 (BM=128) or 2 (BM=64)
  __shared__ __align__(16) unsigned short Alds[BM * 32];
  __shared__ __align__(16) unsigned short Blds[64 * 32];
  const int tid = threadIdx.x;
  const int wave = tid >> 6, lane = tid & 63;
  const int wr = wave >> 1, wc = wave & 1;
  const int row0 = blockIdx.y * BM, col0 = blockIdx.x * 64;

  f32x4 acc[MREP][2];
#pragma unroll
  for (int i = 0; i < MREP; ++i)
#pragma unroll
    for (int j = 0; j < 2; ++j) acc[i][j] = (f32x4){0.f, 0.f, 0.f, 0.f};

  // staging: each gl16 covers 16 rows x 4 kslots (64 lanes x 16B)
  const int rIn = lane >> 2;          // row within 16-row group
  const int jIn = lane & 3;           // dest k-slot (linear)
  const int arow0 = (BM == 128 ? (2 * wave) * 16 : wave * 16) + rIn;
  const int arow1 = (2 * wave + 1) * 16 + rIn;          // used only if BM==128
  const int brow  = wave * 16 + rIn;
  const unsigned short* aSrc0 = A2 + (size_t)(row0 + arow0) * K3 + ((jIn ^ ((arow0 >> 1) & 3)) << 3);
  const unsigned short* aSrc1 = A2 + (size_t)(row0 + (BM == 128 ? arow1 : arow0)) * K3
                                   + ((jIn ^ (((BM == 128 ? arow1 : arow0) >> 1) & 3)) << 3);
  const unsigned short* bSrc  = B2 + (size_t)(col0 + brow) * K3 + ((jIn ^ ((brow >> 1) & 3)) << 3);
  unsigned short* aDst0 = Alds + (BM == 128 ? (2 * wave) * 512 : wave * 512);
  unsigned short* aDst1 = Alds + (BM == 128 ? (2 * wave + 1) * 512 : wave * 512);
  unsigned short* bDst  = Blds + wave * 512;

  const int lrow = lane & 15, kslot = lane >> 4;

  for (int kt = 0; kt < K3; kt += 32) {
    __syncthreads();                   // all waves done reading previous tile
    gl16(aSrc0 + kt, aDst0);
    if constexpr (BM == 128) gl16(aSrc1 + kt, aDst1);
    gl16(bSrc + kt, bDst);
    __syncthreads();                   // drains vmcnt -> tile visible

    bf16x8 af[MREP], bf[2];
#pragma unroll
    for (int m = 0; m < MREP; ++m) {
      const int r = wr * (BM / 2) + m * 16 + lrow;
      af[m] = *(const bf16x8*)(Alds + r * 32 + ((kslot ^ ((r >> 1) & 3)) << 3));
    }
#pragma unroll
    for (int n = 0; n < 2; ++n) {
      const int r = wc * 32 + n * 16 + lrow;
      bf[n] = *(const bf16x8*)(Blds + r * 32 + ((kslot ^ ((r >> 1) & 3)) << 3));
    }
#pragma unroll
    for (int m = 0; m < MREP; ++m)
#pragma unroll
      for (int n = 0; n < 2; ++n)
        acc[m][n] = __builtin_amdgcn_mfma_f32_16x16x32_bf16(af[m], bf[n], acc[m][n], 0, 0, 0);
  }

#pragma unroll
  for (int m = 0; m < MREP; ++m)
#pragma unroll
    for (int n = 0; n < 2; ++n)
#pragma unroll
      for (int r = 0; r < 4; ++r) {
        const int row = row0 + wr * (BM / 2) + m * 16 + (lane >> 4) * 4 + r;
        const int col = col0 + wc * 32 + n * 16 + (lane & 15);
        float v = acc[m][n][r];
        if (MODE == 0) {
          const int sel = col >> 9;
          const int c = col & 511;
          const int bb = row >> 10, nn = row & 1023;
          if (sel == 0) {
            float vv = v + bq[c];
            qbuf[(size_t)row * 512 + c] = vv;
            unsigned short hi = f2b(vv), lo = f2b(vv - b2f(hi));
            size_t mq = (size_t)row * 8 + (c >> 6);
            int kq = c & 63;
            A2q[mq * 192 + kq] = hi;
            A2q[mq * 192 + 64 + kq] = lo;
            A2q[mq * 192 + 128 + kq] = hi;
          } else if (sel == 1) {
            bank[((size_t)(bb * 8 + (c >> 6)) * TOTV + nn) * 64 + (c & 63)] = v + bv[c];
          } else if (sel == 2) {
            klbuf[(size_t)row * 512 + c] = v + bkl[c];
          } else if (sel == 3) {
            vlbuf[(size_t)row * 512 + c] = v + bvl[c];
          } else {
            gatebuf[(size_t)row * 512 + c] = sigmoidf_(v + bgt[c]);
          }
        } else if (MODE == 1) {
          Qs[((size_t)(col >> 6) * 16384 + row) * 64 + (col & 63)] = v;
        } else {
          oout[(size_t)row * 512 + col] = v + ob[col];
        }
      }
}

// ---------------- tree level v5: transposed+packed LDS weights, readlane gin broadcast ----------------
template<int D, int NPB>
__global__ __launch_bounds__(512)
void level5(const float* __restrict__ glW, const float* __restrict__ glb,
            const float* __restrict__ grW, const float* __restrict__ grb,
            const float* __restrict__ pq, const float* __restrict__ lnG,
            const float* __restrict__ lnB, const float* __restrict__ skA,
            const float* __restrict__ skW, const float* __restrict__ coup,
            const float* __restrict__ wfreq, const float* __restrict__ wdamp,
            const float* __restrict__ wphase, float* __restrict__ bank)
{
  constexpr int KPREV = ((D - 1) >= 3) ? 8 : (1 << (D - 1));
  constexpr int SLOTS = 2 * KPREV;
  constexpr int KP = (D >= 3) ? 8 : (1 << D);
  constexpr bool TP = (D >= 3);
  constexpr int VB_PREV = vbase_of(D - 1);
  constexpr int VB_CUR  = vbase_of(D);

  __shared__ __align__(8)  float wpk[128 * 130];
  __shared__ float sklds[64 * 65];
  __shared__ float parlds[8][KP][64];
  __shared__ __align__(16) float slds[TP ? 8 * SLOTS * 68 : 1];
  __shared__ float wlds[TP ? 8 * KP * 17 : 1];
  __shared__ __align__(16) float pqlds[TP ? KP * 68 : 1];

  const int tid = threadIdx.x;
  const int h = tid >> 6, lane = tid & 63;
  const int b = blockIdx.y;

  for (int i = tid; i < 64 * 128; i += 512) {
    int o = i >> 7, e = i & 127;
    wpk[e * 130 + 2 * o]     = glW[(size_t)D * 8192 + i];
    wpk[e * 130 + 2 * o + 1] = grW[(size_t)D * 8192 + i];
  }
  for (int i = tid; i < 64 * 64; i += 512) {
    int o = i >> 6, e = i & 63;
    sklds[e * 65 + o] = skW[(size_t)D * 4096 + i];
  }
  if constexpr (TP) {
    for (int i = tid; i < KP * 64; i += 512)
      pqlds[(i >> 6) * 68 + (i & 63)] = pq[(size_t)D * 512 + i];
  }
  __syncthreads();

  const float alpha = log1pf(__expf(wdamp[h]));
  const float dec = __expf(-alpha);
  const float ang = wfreq[h] + wphase[h] + (float)D * 0.78539816339744831f;
  const float pr  = dec * cosf(ang);
  const float pim = dec * sinf(ang);
  const float glbv = glb[D * 64 + lane], grbv = grb[D * 64 + lane];
  const float lnGv = lnG[D * 64 + lane], lnBv = lnB[D * 64 + lane];
  const float sig_sk = sigmoidf_(skA[D]);
  float cw[8];
  float cmx = -1e30f;
#pragma unroll
  for (int j = 0; j < 8; ++j) { cw[j] = coup[(size_t)(D * 8 + h) * 8 + j]; cmx = fmaxf(cmx, cw[j]); }
  float cs = 0.f;
#pragma unroll
  for (int j = 0; j < 8; ++j) { cw[j] = __expf(cw[j] - cmx); cs += cw[j]; }
  const float cinv = 1.f / cs;

  const size_t bh = (size_t)(b * H_ + h);
  const float* prevb = bank + (bh * TOTV + VB_PREV) * 64;
  float* curb = bank + (bh * TOTV + VB_CUR) * 64;

  for (int nn = 0; nn < NPB; ++nn) {
    const int node = blockIdx.x * NPB + nn;
    float par[KP];
    float fL[KPREV], rot[KPREV];
    {
      float lm = 0.f, rm = 0.f;
#pragma unroll
      for (int k = 0; k < KPREV; ++k) {
        fL[k] = prevb[(size_t)((2 * node) * KPREV + k) * 64 + lane];
        float fr = prevb[(size_t)((2 * node + 1) * KPREV + k) * 64 + lane];
        float partner = __shfl_xor(fr, 32);
        rot[k] = (lane < 32) ? (pr * fr - pim * partner) : (pim * partner + pr * fr);
        lm += fL[k]; rm += rot[k];
      }
      lm *= (1.f / KPREV); rm *= (1.f / KPREV);

      float gl = glbv, gr = grbv, sk = 0.f;
#pragma unroll
      for (int e = 0; e < 64; ++e) {
        float g = rl(lm, e);
        float2 w2 = *(const float2*)&wpk[e * 130 + 2 * lane];
        gl += g * w2.x;
        gr += g * w2.y;
        sk += g * sklds[e * 65 + lane];
      }
#pragma unroll
      for (int e = 0; e < 64; ++e) {
        float g = rl(rm, e);
        float2 w2 = *(const float2*)&wpk[(64 + e) * 130 + 2 * lane];
        gl += g * w2.x;
        gr += g * w2.y;
      }
      gl = sigmoidf_(gl); gr = sigmoidf_(gr);

      float slot[SLOTS];
#pragma unroll
      for (int k = 0; k < KPREV; ++k) { slot[k] = fL[k] * gl; slot[KPREV + k] = rot[k] * gr; }

      if constexpr (!TP) {
        float pqv[KP];
#pragma unroll
        for (int qi = 0; qi < KP; ++qi) pqv[qi] = pq[(size_t)(D * 8 + qi) * 64 + lane];
#pragma unroll
        for (int qi = 0; qi < KP; ++qi) {
          float lg[SLOTS];
          float mx = -1e30f;
#pragma unroll
          for (int kk = 0; kk < SLOTS; ++kk) {
            lg[kk] = wsum(pqv[qi] * slot[kk]) * 0.125f;
            mx = fmaxf(mx, lg[kk]);
          }
          float den = 0.f, pv = 0.f;
#pragma unroll
          for (int kk = 0; kk < SLOTS; ++kk) {
            float w = __expf(lg[kk] - mx);
            den += w; pv += w * slot[kk];
          }
          par[qi] = pv / den;
        }
      } else {
        float* sl = &slds[h * SLOTS * 68];
#pragma unroll
        for (int kk = 0; kk < SLOTS; ++kk) sl[kk * 68 + lane] = slot[kk];
        constexpr int PAIRS = KP * SLOTS;
        const int kk0 = lane & (SLOTS - 1);
        const int qg  = lane / SLOTS;
        float s0 = 0.f, s1 = 0.f;
        {
          const float4* sv = (const float4*)&sl[kk0 * 68];
          const float4* q0 = (const float4*)&pqlds[qg * 68];
#pragma unroll
          for (int e = 0; e < 16; ++e) s0 += dot4(q0[e], sv[e]);
          if constexpr (PAIRS == 128) {
            const float4* q1 = (const float4*)&pqlds[(qg + 4) * 68];
#pragma unroll
            for (int e = 0; e < 16; ++e) s1 += dot4(q1[e], sv[e]);
          }
        }
        s0 *= 0.125f; s1 *= 0.125f;
        float m0 = s0, m1 = s1;
#pragma unroll
        for (int o = 1; o < SLOTS; o <<= 1) {
          m0 = fmaxf(m0, __shfl_xor(m0, o));
          if constexpr (PAIRS == 128) m1 = fmaxf(m1, __shfl_xor(m1, o));
        }
        float e0 = __expf(s0 - m0), e1 = (PAIRS == 128) ? __expf(s1 - m1) : 0.f;
        float d0 = e0, d1 = e1;
#pragma unroll
        for (int o = 1; o < SLOTS; o <<= 1) {
          d0 += __shfl_xor(d0, o);
          if constexpr (PAIRS == 128) d1 += __shfl_xor(d1, o);
        }
        float* wld = &wlds[h * KP * 17];
        wld[qg * 17 + kk0] = e0 / d0;
        if constexpr (PAIRS == 128) wld[(qg + 4) * 17 + kk0] = e1 / d1;
#pragma unroll
        for (int qi = 0; qi < KP; ++qi) {
          float acc2 = 0.f;
#pragma unroll
          for (int kk = 0; kk < SLOTS; ++kk) acc2 += wld[qi * 17 + kk] * slot[kk];
          par[qi] = acc2;
        }
      }

#pragma unroll
      for (int qi = 0; qi < KP; ++qi) {
        float mu = wsum(par[qi]) * (1.f / 64.f);
        float dv = par[qi] - mu;
        float var = wsum(dv * dv) * (1.f / 64.f);
        float nv = dv * rsqrtf(var + 1e-5f);
        par[qi] = nv * lnGv + lnBv + sig_sk * sk;
        parlds[h][qi][lane] = par[qi];
      }
    }
    __syncthreads();
#pragma unroll
    for (int qi = 0; qi < KP; ++qi) {
      float o = 0.f;
#pragma unroll
      for (int j = 0; j < 8; ++j) o += cw[j] * parlds[j][qi][lane];
      curb[(size_t)(node * KP + qi) * 64 + lane] = o * cinv;
    }
    __syncthreads();
  }
}

// ---------------- combine v3: XCD swizzle + 4-lane score gather + unrolled PV ----------------
__global__ __launch_bounds__(512)
void combine3(const float* __restrict__ qbuf, const float* __restrict__ klbuf,
              const float* __restrict__ vlbuf, const float* __restrict__ gatebuf,
              const float* __restrict__ bank, const float* __restrict__ Qs,
              unsigned short* __restrict__ A2o)
{
  const int flat = blockIdx.y * 1024 + blockIdx.x;
  const int swz = (flat & 7) * 256 + (flat >> 3);
  const int n = swz & 1023;
  const int b = swz >> 10;
  const int h = threadIdx.x >> 6;
  const int lane = threadIdx.x & 63;
  __shared__ int pair_ro[64];
  __shared__ int pair_sl[64];
  __shared__ int sdepth[16];
  __shared__ int PS[2];
  __shared__ __align__(16) float Qlds[8][10][68];
  __shared__ __align__(16) float qlds[8][64];
  __shared__ float sclds[8][64];

  if (threadIdx.x == 0) {
    int l = 2048, r = 2048 + n;
    int cnt = 0, sc = 0;
    while (l < r) {
      if (l & 1) {
        int m = l++;
        int j = 31 - __clz(m);
        int d = 11 - j;
        int local = m - (1 << j);
        int kv = (d >= 3) ? 8 : (1 << d);
        sdepth[sc] = d;
        int vb = VBASE[d] + local * kv;
        for (int k = 0; k < kv; ++k) { pair_ro[cnt] = (vb + k) * 64; pair_sl[cnt] = sc; ++cnt; }
        ++sc;
      }
      if (r & 1) {
        int m = --r;
        int j = 31 - __clz(m);
        int d = 11 - j;
        int local = m - (1 << j);
        int kv = (d >= 3) ? 8 : (1 << d);
        sdepth[sc] = d;
        int vb = VBASE[d] + local * kv;
        for (int k = 0; k < kv; ++k) { pair_ro[cnt] = (vb + k) * 64; pair_sl[cnt] = sc; ++cnt; }
        ++sc;
      }
      l >>= 1; r >>= 1;
    }
    PS[0] = cnt; PS[1] = sc;
    for (int k = cnt; k < 64; ++k) { pair_ro[k] = 0; pair_sl[k] = 0; }
  }
  const size_t vbase = ((size_t)(b * N_ + n) * H_ + h) * 64;
  qlds[h][lane] = qbuf[vbase + lane];   // wave-local
  __syncthreads();
  const int P = PS[0], S = PS[1];

  for (int s = 0; s < S; ++s)
    Qlds[h][s][lane] = Qs[((size_t)sdepth[s] * 16384 + (size_t)(b * N_ + n) * H_ + h) * 64 + lane];

  // ---- local sliding-window attention ----
  const int w = lane & 31, half = lane >> 5;
  const int wmax = (n + 1 < 32) ? (n + 1) : 32;
  float scl = 0.f;
  if (w < wmax) {
    const float4* k4 = (const float4*)(klbuf + vbase - (size_t)w * 512 + half * 32);
    const float4* q4 = (const float4*)&qlds[h][half * 32];
#pragma unroll
    for (int e = 0; e < 8; ++e) scl += dot4(q4[e], k4[e]);
  }
  scl += __shfl_xor(scl, 32);
  scl *= 0.125f;
  float sm = (w < wmax) ? scl : -1e30f;
  float mx = sm;
#pragma unroll
  for (int o = 1; o < 32; o <<= 1) mx = fmaxf(mx, __shfl_xor(mx, o));
  float le = (w < wmax) ? __expf(sm - mx) : 0.f;
  float den = le;
#pragma unroll
  for (int o = 1; o < 32; o <<= 1) den += __shfl_xor(den, o);
  float lp = le / den;
  float local = 0.f;
  if (n >= 31) {
#pragma unroll 8
    for (int ww = 0; ww < 32; ++ww) {
      float pw = __shfl(lp, ww);
      local += pw * vlbuf[vbase - (size_t)ww * 512 + lane];
    }
  } else {
    for (int ww = 0; ww < wmax; ++ww) {
      float pw = __shfl(lp, ww);
      local += pw * vlbuf[vbase - (size_t)ww * 512 + lane];
    }
  }

  // ---- tree attention: 4 lanes per pair ----
  const size_t bhbase = (size_t)(b * H_ + h) * TOTV * 64;
  float tree = 0.f;
  if (P > 0) {
    const int passes = (P + 15) >> 4;
    for (int t = 0; t < passes; ++t) {
      const int p = (t << 4) + (lane >> 2);
      const int c = lane & 3;
      float s = 0.f;
      if (p < P) {
        const float4* b4 = (const float4*)(bank + bhbase + pair_ro[p] + c * 16);
        const float4* q4 = (const float4*)&Qlds[h][pair_sl[p]][c * 16];
#pragma unroll
        for (int i = 0; i < 4; ++i) s += dot4(q4[i], b4[i]);
      }
      s += __shfl_xor(s, 1);
      s += __shfl_xor(s, 2);
      if (c == 0 && p < P) sclds[h][p] = s;
    }
    float logit = (lane < P) ? sclds[h][lane] : -1e30f;
    float tm = logit;
#pragma unroll
    for (int o = 1; o < 64; o <<= 1) tm = fmaxf(tm, __shfl_xor(tm, o));
    float te = (lane < P) ? __expf(logit - tm) : 0.f;
    float tden = te;
#pragma unroll
    for (int o = 1; o < 64; o <<= 1) tden += __shfl_xor(tden, o);
    float tw = te / tden;
    const int P4 = (P + 3) & ~3;
    for (int l2 = 0; l2 < P4; l2 += 4) {
      float w0_ = __shfl(tw, l2),     w1_ = __shfl(tw, l2 + 1);
      float w2_ = __shfl(tw, l2 + 2), w3_ = __shfl(tw, l2 + 3);
      float v0 = bank[bhbase + pair_ro[l2]     + lane];
      float v1 = bank[bhbase + pair_ro[l2 + 1] + lane];
      float v2 = bank[bhbase + pair_ro[l2 + 2] + lane];
      float v3 = bank[bhbase + pair_ro[l2 + 3] + lane];
      tree += w0_ * v0 + w1_ * v1 + w2_ * v2 + w3_ * v3;
    }
  }

  float g = gatebuf[vbase + lane];
  float v = local + g * tree;
  unsigned short hi = f2b(v), lo = f2b(v - b2f(hi));
  const size_t m = (size_t)(b * N_ + n);
  const int k = h * 64 + lane;
  A2o[m * 1536 + k] = hi;
  A2o[m * 1536 + 512 + k] = lo;
  A2o[m * 1536 + 1024 + k] = hi;
}

// ---------------- launcher ----------------
extern "C" void kernel_launch(void* const* d_in, const int* in_sizes, int n_in,
                              void* d_out, int out_size, void* d_ws, size_t ws_size,
                              hipStream_t stream)
{
  (void)in_sizes; (void)n_in; (void)out_size; (void)ws_size;
  const float* x     = (const float*)d_in[0];
  const float* qW    = (const float*)d_in[1];
  const float* qb    = (const float*)d_in[2];
  const float* vW    = (const float*)d_in[3];
  const float* vb    = (const float*)d_in[4];
  const float* oW    = (const float*)d_in[5];
  const float* ob    = (const float*)d_in[6];
  const float* klW   = (const float*)d_in[7];
  const float* klb   = (const float*)d_in[8];
  const float* vlW   = (const float*)d_in[9];
  const float* vlb   = (const float*)d_in[10];
  const float* gW    = (const float*)d_in[11];
  const float* gb    = (const float*)d_in[12];
  const float* ddqW  = (const float*)d_in[13];
  const float* ddqT  = (const float*)d_in[14];
  const float* wfreq = (const float*)d_in[15];
  const float* wdamp = (const float*)d_in[16];
  const float* wphase= (const float*)d_in[17];
  const float* glW   = (const float*)d_in[18];
  const float* glb   = (const float*)d_in[19];
  const float* grW   = (const float*)d_in[20];
  const float* grb   = (const float*)d_in[21];
  const float* pq    = (const float*)d_in[22];
  const float* lnG   = (const float*)d_in[23];
  const float* lnB   = (const float*)d_in[24];
  const float* skA   = (const float*)d_in[25];
  const float* skW   = (const float*)d_in[26];
  const float* coup  = (const float*)d_in[27];

  float* ws = (float*)d_ws;
  float* qbuf    = ws; ws += (size_t)2048 * 512;
  float* klbuf   = ws; ws += (size_t)2048 * 512;
  float* vlbuf   = ws; ws += (size_t)2048 * 512;
  float* gatebuf = ws; ws += (size_t)2048 * 512;
  float* bank    = ws; ws += (size_t)16 * TOTV * 64;
  float* Qs      = ws; ws += (size_t)10 * 16384 * 64;
  unsigned short* A2x = (unsigned short*)ws; ws += (size_t)2048 * 1536 / 2;
  unsigned short* B2w = (unsigned short*)ws; ws += (size_t)2560 * 1536 / 2;
  unsigned short* A2q = (unsigned short*)ws; ws += (size_t)16384 * 192 / 2;
  unsigned short* B2q = (unsigned short*)ws; ws += (size_t)640 * 192 / 2;
  unsigned short* A2o = (unsigned short*)ws; ws += (size_t)2048 * 1536 / 2;
  unsigned short* B2o = (unsigned short*)ws; ws += (size_t)512 * 1536 / 2;

  prep_kernel<<<2720, 256, 0, stream>>>(x, qW, vW, klW, vlW, gW, oW, ddqW, ddqT,
                                        A2x, B2w, B2o, B2q);

  gemm_mfma<0, 128><<<dim3(40, 16), 256, 0, stream>>>(A2x, B2w, 1536,
      qb, vb, klb, vlb, gb, qbuf, bank, klbuf, vlbuf, gatebuf,
      nullptr, nullptr, nullptr, A2q);

  gemm_mfma<1, 128><<<dim3(10, 128), 256, 0, stream>>>(A2q, B2q, 192,
      nullptr, nullptr, nullptr, nullptr, nullptr,
      nullptr, nullptr, nullptr, nullptr, nullptr, Qs, nullptr, nullptr, nullptr);

#define LVL(DD, NPB) level5<DD, NPB><<<dim3((1024 >> DD) / NPB, 2), 512, 0, stream>>>( \
      glW, glb, grW, grb, pq, lnG, lnB, skA, skW, coup, wfreq, wdamp, wphase, bank)
  LVL(1, 4); LVL(2, 2); LVL(3, 1); LVL(4, 1); LVL(5, 1);
  LVL(6, 1); LVL(7, 1); LVL(8, 1); LVL(9, 1);
#undef LVL

  combine3<<<dim3(1024, 2), 512, 0, stream>>>(qbuf, klbuf, vlbuf, gatebuf, bank, Qs, A2o);

  gemm_mfma<2, 64><<<dim3(8, 32), 256, 0, stream>>>(A2o, B2o, 1536,
      nullptr, nullptr, nullptr, nullptr, nullptr,
      nullptr, nullptr, nullptr, nullptr, nullptr, nullptr,
      (float*)d_out, ob, nullptr);
}